// Round 1
// baseline (1526.401 us; speedup 1.0000x reference)
//
#include <hip/hip_runtime.h>

typedef float v4f __attribute__((ext_vector_type(4)));

#define K 128
#define VC 64
#define W_BIJ 1000.0f
#define W_ORTH 1000.0f
#define W_LAP 1.0f
#define W_PRE 100000.0f

// One fused kernel, block-specialized:
//   blocks [0, N*ND)        : l_pre path, one block per (n, d)
//   blocks [N*ND, N*ND+4*N) : small losses, one block per (n, p), p in {bij1,bij2,orth1,orth2}
// Dynamic LDS: max(32768, 2*128*129) floats = 132096 bytes (needs opt-in > 64KB).
extern "C" __global__ __launch_bounds__(256, 1)
void surfm_fused(const float* __restrict__ C12g, const float* __restrict__ C21g,
                 const float* __restrict__ F1, const float* __restrict__ F2,
                 const float* __restrict__ E1, const float* __restrict__ E2,
                 const float* __restrict__ T1, const float* __restrict__ T2,
                 const float* __restrict__ ev1g, const float* __restrict__ ev2g,
                 const int* __restrict__ desc, float* __restrict__ out,
                 int N, int ND, int V)
{
    extern __shared__ float lds[];
    const int b   = blockIdx.x;
    const int tid = threadIdx.x;
    const int nPre = N * ND;
    const int tx = tid & 15, ty = tid >> 4;

    if (b < nPre) {
        // ------------------------------ l_pre path ------------------------------
        const int n = b / ND, d = b - (b / ND) * ND;
        const int col = desc[d];
        const float* A1g = T1 + (size_t)n * K * V;      // evecs_trans1[n]: [K][V]
        const float* A2g = T2 + (size_t)n * K * V;
        const float* B1g = E1 + (size_t)n * V * K;      // evecs_1[n]: [V][K]
        const float* B2g = E2 + (size_t)n * V * K;
        const float* w1g = F1 + (size_t)n * V * K + col; // feat_1[n][v][col] at stride K
        const float* w2g = F2 + (size_t)n * V * K + col;

        float* As1 = lds;                      // [K][VC], col-groups XOR-swizzled by (r>>3)
        float* As2 = lds + K * VC;
        float* Bs1 = lds + 2 * K * VC;         // [VC][K], row-major (row reads are CF)
        float* Bs2 = lds + 2 * K * VC + VC * K;

        const int r0 = ty * 8;                 // 8 output rows per thread
        const int ca = tx * 4, cb = 64 + tx * 4; // two 4-col groups per thread
        const int kcol = ty & 7;               // swizzle key for this thread's M rows

        v4f acc1a[8], acc1b[8], acc2a[8], acc2b[8];
        #pragma unroll
        for (int i = 0; i < 8; ++i) {
            acc1a[i] = (v4f){0,0,0,0}; acc1b[i] = (v4f){0,0,0,0};
            acc2a[i] = (v4f){0,0,0,0}; acc2b[i] = (v4f){0,0,0,0};
        }

        for (int v0 = 0; v0 < V; v0 += VC) {
            __syncthreads();   // protect LDS from previous chunk's readers
            // ---- stage A chunks (K x VC each), swizzled ----
            #pragma unroll
            for (int it = 0; it < (K * VC / 4) / 256; ++it) {
                const int i  = it * 256 + tid;
                const int r  = i >> 4;          // 16 float4 groups per row
                const int vg = i & 15;
                const int v  = v0 + vg * 4;
                v4f a1 = {0,0,0,0}, a2 = {0,0,0,0};
                if (v + 3 < V) {               // V % 4 == 0 so full-vec path is aligned
                    a1 = *(const v4f*)(A1g + (size_t)r * V + v);
                    a2 = *(const v4f*)(A2g + (size_t)r * V + v);
                } else {
                    #pragma unroll
                    for (int e = 0; e < 4; ++e)
                        if (v + e < V) { a1[e] = A1g[(size_t)r * V + v + e];
                                         a2[e] = A2g[(size_t)r * V + v + e]; }
                }
                const int sg = vg ^ (r >> 3);  // swizzle: column reads become CF
                *(v4f*)(As1 + r * VC + sg * 4) = a1;
                *(v4f*)(As2 + r * VC + sg * 4) = a2;
            }
            // ---- stage B chunks (VC x K each), w folded in ----
            #pragma unroll
            for (int it = 0; it < (VC * K / 4) / 256; ++it) {
                const int i  = it * 256 + tid;
                const int v  = i >> 5;          // 32 float4 groups per row
                const int cg = i & 31;
                const int vg = v0 + v;
                v4f b1 = {0,0,0,0}, b2 = {0,0,0,0};
                if (vg < V) {
                    const float w1 = w1g[(size_t)vg * K];
                    const float w2 = w2g[(size_t)vg * K];
                    b1 = *(const v4f*)(B1g + (size_t)vg * K + cg * 4) * w1;
                    b2 = *(const v4f*)(B2g + (size_t)vg * K + cg * 4) * w2;
                }
                *(v4f*)(Bs1 + v * K + cg * 4) = b1;
                *(v4f*)(Bs2 + v * K + cg * 4) = b2;
            }
            __syncthreads();
            // ---- accumulate M1 += A1 * (w1.B1), M2 += A2 * (w2.B2) over this chunk ----
            #pragma unroll 4
            for (int vg4 = 0; vg4 < VC / 4; ++vg4) {
                const int sg = vg4 ^ ty;        // matches staging swizzle ((r>>3)==ty for r in tile)
                const float* pa1 = As1 + r0 * VC + sg * 4;
                const float* pa2 = As2 + r0 * VC + sg * 4;
                v4f a1v[8], a2v[8];
                #pragma unroll
                for (int i = 0; i < 8; ++i) {
                    a1v[i] = *(const v4f*)(pa1 + i * VC);
                    a2v[i] = *(const v4f*)(pa2 + i * VC);
                }
                #pragma unroll
                for (int j = 0; j < 4; ++j) {
                    const int v = vg4 * 4 + j;
                    const v4f b1a = *(const v4f*)(Bs1 + v * K + ca);
                    const v4f b1b = *(const v4f*)(Bs1 + v * K + cb);
                    const v4f b2a = *(const v4f*)(Bs2 + v * K + ca);
                    const v4f b2b = *(const v4f*)(Bs2 + v * K + cb);
                    #pragma unroll
                    for (int i = 0; i < 8; ++i) {
                        const float a1 = a1v[i][j], a2 = a2v[i][j];
                        acc1a[i] += b1a * a1; acc1b[i] += b1b * a1;
                        acc2a[i] += b2a * a2; acc2b[i] += b2b * a2;
                    }
                }
            }
        }
        __syncthreads();
        // ---- write M1, M2 to LDS (col-group XOR swizzle by row's (r>>3)&7) ----
        float* M1 = lds;            // [K][K]
        float* M2 = lds + K * K;
        #pragma unroll
        for (int i = 0; i < 8; ++i) {
            const int r  = r0 + i;
            const int ga = (tx ^ kcol) << 2;
            const int gb = ((16 + tx) ^ kcol) << 2;
            *(v4f*)(M1 + r * K + ga) = acc1a[i];
            *(v4f*)(M1 + r * K + gb) = acc1b[i];
            *(v4f*)(M2 + r * K + ga) = acc2a[i];
            *(v4f*)(M2 + r * K + gb) = acc2b[i];
        }
        __syncthreads();

        // ---- stage 2: r1 = C12*M1 - M2*C12, r2 = C21*M2 - M1*C21; sum of squares ----
        const float* c12 = C12g + (size_t)n * K * K;
        const float* c21 = C21g + (size_t)n * K * K;
        #pragma unroll
        for (int i = 0; i < 8; ++i) {
            acc1a[i] = (v4f){0,0,0,0}; acc1b[i] = (v4f){0,0,0,0};
            acc2a[i] = (v4f){0,0,0,0}; acc2b[i] = (v4f){0,0,0,0};
        }
        for (int j = 0; j < K; ++j) {
            const int keyj = (j >> 3) & 7;
            const int ga = (tx ^ keyj) << 2;
            const int gb = ((16 + tx) ^ keyj) << 2;
            const v4f m1ra = *(const v4f*)(M1 + j * K + ga);
            const v4f m1rb = *(const v4f*)(M1 + j * K + gb);
            const v4f m2ra = *(const v4f*)(M2 + j * K + ga);
            const v4f m2rb = *(const v4f*)(M2 + j * K + gb);
            const v4f c12ra = *(const v4f*)(c12 + j * K + ca);
            const v4f c12rb = *(const v4f*)(c12 + j * K + cb);
            const v4f c21ra = *(const v4f*)(c21 + j * K + ca);
            const v4f c21rb = *(const v4f*)(c21 + j * K + cb);
            const int jp = (((j >> 2) ^ kcol) << 2) | (j & 3);  // physical col of logical j
            #pragma unroll
            for (int i = 0; i < 8; ++i) {
                const int r = r0 + i;
                const float x12 = c12[r * K + j];
                const float x21 = c21[r * K + j];
                const float m1c = M1[r * K + jp];
                const float m2c = M2[r * K + jp];
                acc1a[i] += m1ra * x12; acc1a[i] -= c12ra * m2c;
                acc1b[i] += m1rb * x12; acc1b[i] -= c12rb * m2c;
                acc2a[i] += m2ra * x21; acc2a[i] -= c21ra * m1c;
                acc2b[i] += m2rb * x21; acc2b[i] -= c21rb * m1c;
            }
        }
        float s = 0.0f;
        #pragma unroll
        for (int i = 0; i < 8; ++i) {
            #pragma unroll
            for (int e = 0; e < 4; ++e) {
                s += acc1a[i][e] * acc1a[i][e] + acc1b[i][e] * acc1b[i][e];
                s += acc2a[i][e] * acc2a[i][e] + acc2b[i][e] * acc2b[i][e];
            }
        }
        #pragma unroll
        for (int off = 32; off; off >>= 1) s += __shfl_down(s, off, 64);
        if ((tid & 63) == 0)
            atomicAdd(out + 3, s * (W_PRE / (float)(N * K * K)));
    } else {
        // --------------------------- small losses path ---------------------------
        const int idx = b - nPre;
        const int n = idx >> 2, p = idx & 3;
        const float* c12 = C12g + (size_t)n * K * K;
        const float* c21 = C21g + (size_t)n * K * K;
        const float* Xg = (p == 1 || p == 3) ? c21 : c12;
        const float* Yg = (p == 0) ? c21 : c12;            // only used for p < 2
        const float* ea = (p == 0) ? ev1g + n * K : ev2g + n * K; // lap: over cols j
        const float* eb = (p == 0) ? ev2g + n * K : ev1g + n * K; // lap: over rows i
        float* X = lds;             // [K][129]
        float* Y = lds + K * 129;
        float lap = 0.0f;
        for (int i = tid; i < K * K / 4; i += 256) {
            const int r = i >> 5, c4 = (i & 31) * 4;
            const v4f x = *(const v4f*)(Xg + r * K + c4);
            X[r * 129 + c4 + 0] = x[0]; X[r * 129 + c4 + 1] = x[1];
            X[r * 129 + c4 + 2] = x[2]; X[r * 129 + c4 + 3] = x[3];
            if (p < 2) {
                const v4f y = *(const v4f*)(Yg + r * K + c4);
                Y[r * 129 + c4 + 0] = y[0]; Y[r * 129 + c4 + 1] = y[1];
                Y[r * 129 + c4 + 2] = y[2]; Y[r * 129 + c4 + 3] = y[3];
                const float ebi = eb[r];
                #pragma unroll
                for (int e = 0; e < 4; ++e) {
                    const float dlt = ea[c4 + e] - ebi;
                    lap += x[e] * x[e] * dlt * dlt;
                }
            }
        }
        __syncthreads();
        const int i0 = ty * 8, k0 = tx * 8;
        float z[8][8];
        #pragma unroll
        for (int i = 0; i < 8; ++i)
            #pragma unroll
            for (int t = 0; t < 8; ++t) z[i][t] = 0.0f;
        for (int j = 0; j < K; ++j) {
            float xi[8], yk[8];
            if (p < 2) {   // Z = X @ Y
                #pragma unroll
                for (int i = 0; i < 8; ++i) xi[i] = X[(i0 + i) * 129 + j];
                #pragma unroll
                for (int t = 0; t < 8; ++t) yk[t] = Y[j * 129 + k0 + t];
            } else {       // Z = X^T @ X
                #pragma unroll
                for (int i = 0; i < 8; ++i) xi[i] = X[j * 129 + i0 + i];
                #pragma unroll
                for (int t = 0; t < 8; ++t) yk[t] = X[j * 129 + k0 + t];
            }
            #pragma unroll
            for (int i = 0; i < 8; ++i)
                #pragma unroll
                for (int t = 0; t < 8; ++t) z[i][t] += xi[i] * yk[t];
        }
        float s = 0.0f;
        #pragma unroll
        for (int i = 0; i < 8; ++i) {
            #pragma unroll
            for (int t = 0; t < 8; ++t) {
                const float e = z[i][t] - ((i0 + i) == (k0 + t) ? 1.0f : 0.0f);
                s += e * e;
            }
        }
        #pragma unroll
        for (int off = 32; off; off >>= 1) {
            s   += __shfl_down(s, off, 64);
            lap += __shfl_down(lap, off, 64);
        }
        if ((tid & 63) == 0) {
            if (p < 2) {
                atomicAdd(out + 0, s * (W_BIJ / (float)N));
                atomicAdd(out + 2, lap * (W_LAP / (float)N));
            } else {
                atomicAdd(out + 1, s * (W_ORTH / (float)N));
            }
        }
    }
}

extern "C" void kernel_launch(void* const* d_in, const int* in_sizes, int n_in,
                              void* d_out, int out_size, void* d_ws, size_t ws_size,
                              hipStream_t stream) {
    (void)n_in; (void)d_ws; (void)ws_size;
    const float* C12 = (const float*)d_in[0];
    const float* C21 = (const float*)d_in[1];
    const float* F1  = (const float*)d_in[2];
    const float* F2  = (const float*)d_in[3];
    const float* E1  = (const float*)d_in[4];
    const float* E2  = (const float*)d_in[5];
    const float* T1  = (const float*)d_in[6];
    const float* T2  = (const float*)d_in[7];
    const float* ev1 = (const float*)d_in[8];
    const float* ev2 = (const float*)d_in[9];
    const int* desc  = (const int*)d_in[10];
    float* out = (float*)d_out;

    const int N  = in_sizes[8] / K;            // evals_1: N*K
    const int ND = in_sizes[10];               // desc_ind
    const int V  = in_sizes[4] / (N * K);      // evecs_1: N*V*K

    const size_t shmem = (size_t)(2 * K * 129) * sizeof(float);  // 132096 B (> 64KB opt-in)
    hipFuncSetAttribute((const void*)surfm_fused,
                        hipFuncAttributeMaxDynamicSharedMemorySize, (int)shmem);
    hipMemsetAsync(d_out, 0, (size_t)out_size * sizeof(float), stream);

    const int blocks = N * ND + 4 * N;
    surfm_fused<<<blocks, 256, shmem, stream>>>(C12, C21, F1, F2, E1, E2, T1, T2,
                                                ev1, ev2, desc, out, N, ND, V);
}

// Round 2
// 794.970 us; speedup vs baseline: 1.9201x; 1.9201x over previous
//
#include <hip/hip_runtime.h>

typedef float v4f __attribute__((ext_vector_type(4)));
typedef __attribute__((ext_vector_type(8))) short bhalf8;   // 8 bf16 in 4 VGPRs

#define K 128
#define VC 128
#define W_BIJ 1000.0f
#define W_ORTH 1000.0f
#define W_LAP 1.0f
#define W_PRE 100000.0f

static __device__ __forceinline__ unsigned short f2b(float x) {
    union { float f; unsigned int u; } v; v.f = x;
    unsigned int u = v.u + 0x7FFFu + ((v.u >> 16) & 1u);   // RNE
    return (unsigned short)(u >> 16);
}

// blocks [0, N*ND)        : l_pre path, one block per (n, d); n = b & 7 (XCD-aligned)
// blocks [N*ND, N*ND+4*N) : small losses, one block per (n, p)
extern "C" __global__ __launch_bounds__(256, 1)
void surfm_fused(const float* __restrict__ C12g, const float* __restrict__ C21g,
                 const float* __restrict__ F1, const float* __restrict__ F2,
                 const float* __restrict__ E1g, const float* __restrict__ E2g,
                 const float* __restrict__ T1, const float* __restrict__ T2,
                 const float* __restrict__ ev1g, const float* __restrict__ ev2g,
                 const int* __restrict__ desc, float* __restrict__ out,
                 int N, int ND, int V, int CF)
{
    extern __shared__ char smem[];
    const int b   = blockIdx.x;
    const int tid = threadIdx.x;
    const int nPre = N * ND;

    if (b < nPre) {
        // ------------------------------ l_pre path ------------------------------
        const int n = b & 7;          // same-n blocks share an XCD (round-robin dispatch)
        const int d = b >> 3;
        const int col = desc[d];
        const float* A1g = T1 + (size_t)n * K * V;       // evecs_trans1[n]: [K][V]
        const float* A2g = T2 + (size_t)n * K * V;
        const float* B1g = E1g + (size_t)n * V * K;      // evecs_1[n]: [V][K]
        const float* B2g = E2g + (size_t)n * V * K;
        const float* w1g = F1 + (size_t)n * V * CF;      // feat_1[n][v][col]
        const float* w2g = F2 + (size_t)n * V * CF;

        // stage-1 LDS: bf16 tiles (128 KB total)
        char* As1 = smem;                 // A1 chunk [128 rows][VC k] bf16, swz (r&7)<<4
        char* As2 = smem + 32768;
        char* Bt1 = smem + 65536;         // B1^T chunk [128 j][VC v] bf16, swz ((j&7)^((j>>3)&7))<<4
        char* Bt2 = smem + 98304;

        const int l  = tid & 63;
        const int w  = tid >> 6;          // wave id: j-strip [w*32, w*32+32)
        const int lm = l & 15;
        const int lk = (l >> 4) * 8;      // k-offset within MFMA frag

        v4f acc1[8][2], acc2[8][2];
        #pragma unroll
        for (int mf = 0; mf < 8; ++mf)
            #pragma unroll
            for (int jf = 0; jf < 2; ++jf) {
                acc1[mf][jf] = (v4f){0.f,0.f,0.f,0.f};
                acc2[mf][jf] = (v4f){0.f,0.f,0.f,0.f};
            }

        for (int v0 = 0; v0 < V; v0 += VC) {
            __syncthreads();
            // ---- stage A chunks: thread i covers row r = i>>5, cols c4 = (i&31)*4 ----
            #pragma unroll 4
            for (int it = 0; it < 16; ++it) {
                const int i  = it * 256 + tid;
                const int r  = i >> 5;
                const int c4 = (i & 31) * 4;
                const int vg = v0 + c4;
                v4f a1 = {0.f,0.f,0.f,0.f}, a2 = {0.f,0.f,0.f,0.f};
                if (vg < V) {              // V%4==0, v0%VC==0 -> all-or-nothing float4
                    a1 = *(const v4f*)(A1g + (size_t)r * V + vg);
                    a2 = *(const v4f*)(A2g + (size_t)r * V + vg);
                }
                const int byte = (r * (VC*2) + c4 * 2) ^ ((r & 7) << 4);
                short4 p1, p2;
                p1.x = (short)f2b(a1[0]); p1.y = (short)f2b(a1[1]);
                p1.z = (short)f2b(a1[2]); p1.w = (short)f2b(a1[3]);
                p2.x = (short)f2b(a2[0]); p2.y = (short)f2b(a2[1]);
                p2.z = (short)f2b(a2[2]); p2.w = (short)f2b(a2[3]);
                *(short4*)(As1 + byte) = p1;
                *(short4*)(As2 + byte) = p2;
            }
            // ---- stage B^T chunks: thread i covers j4=(i&31)*4, v-pair vp=(i>>5)*2 ----
            #pragma unroll 2
            for (int it = 0; it < 8; ++it) {
                const int i  = it * 256 + tid;
                const int j4 = (i & 31) * 4;
                const int vp = (i >> 5) * 2;
                const int va = v0 + vp, vb = va + 1;
                v4f e1a = {0.f,0.f,0.f,0.f}, e1b = e1a, e2a = e1a, e2b = e1a;
                if (va < V) {
                    const float w1 = w1g[(size_t)va * CF + col];
                    const float w2 = w2g[(size_t)va * CF + col];
                    e1a = *(const v4f*)(B1g + (size_t)va * K + j4) * w1;
                    e2a = *(const v4f*)(B2g + (size_t)va * K + j4) * w2;
                }
                if (vb < V) {
                    const float w1 = w1g[(size_t)vb * CF + col];
                    const float w2 = w2g[(size_t)vb * CF + col];
                    e1b = *(const v4f*)(B1g + (size_t)vb * K + j4) * w1;
                    e2b = *(const v4f*)(B2g + (size_t)vb * K + j4) * w2;
                }
                #pragma unroll
                for (int e = 0; e < 4; ++e) {
                    const int j = j4 + e;
                    const int key = (((j & 7) ^ ((j >> 3) & 7)) << 4);
                    const int byte = (j * (VC*2) + vp * 2) ^ key;
                    *(unsigned int*)(Bt1 + byte) =
                        (unsigned int)f2b(e1a[e]) | ((unsigned int)f2b(e1b[e]) << 16);
                    *(unsigned int*)(Bt2 + byte) =
                        (unsigned int)f2b(e2a[e]) | ((unsigned int)f2b(e2b[e]) << 16);
                }
            }
            __syncthreads();
            // ---- MFMA: M1 += A1*B1, M2 += A2*B2 over this chunk ----
            #pragma unroll
            for (int ks = 0; ks < VC/32; ++ks) {
                const int k0 = ks*32 + lk;
                bhalf8 bB1[2], bB2[2];
                #pragma unroll
                for (int jf = 0; jf < 2; ++jf) {
                    const int j = w*32 + jf*16 + lm;
                    const int key = (((j & 7) ^ ((j >> 3) & 7)) << 4);
                    const int byte = (j * (VC*2) + k0 * 2) ^ key;
                    bB1[jf] = *(const bhalf8*)(Bt1 + byte);
                    bB2[jf] = *(const bhalf8*)(Bt2 + byte);
                }
                #pragma unroll
                for (int mf = 0; mf < 8; ++mf) {
                    const int r = mf*16 + lm;
                    const int byte = (r * (VC*2) + k0 * 2) ^ ((r & 7) << 4);
                    const bhalf8 a1 = *(const bhalf8*)(As1 + byte);
                    const bhalf8 a2 = *(const bhalf8*)(As2 + byte);
                    acc1[mf][0] = __builtin_amdgcn_mfma_f32_16x16x32_bf16(a1, bB1[0], acc1[mf][0], 0, 0, 0);
                    acc1[mf][1] = __builtin_amdgcn_mfma_f32_16x16x32_bf16(a1, bB1[1], acc1[mf][1], 0, 0, 0);
                    acc2[mf][0] = __builtin_amdgcn_mfma_f32_16x16x32_bf16(a2, bB2[0], acc2[mf][0], 0, 0, 0);
                    acc2[mf][1] = __builtin_amdgcn_mfma_f32_16x16x32_bf16(a2, bB2[1], acc2[mf][1], 0, 0, 0);
                }
            }
        }
        __syncthreads();
        // ---- spill accs to fp32 LDS M1/M2 using round-1's swizzle convention ----
        // logical M[row][col] at phys col ((col>>2 ^ ((row>>3)&7))<<2 | (col&3))
        float* M1 = (float*)smem;            // [K][K] fp32
        float* M2 = (float*)smem + K * K;
        #pragma unroll
        for (int mf = 0; mf < 8; ++mf)
            #pragma unroll
            for (int jf = 0; jf < 2; ++jf)
                #pragma unroll
                for (int rg = 0; rg < 4; ++rg) {
                    const int row = mf*16 + ((l >> 4) << 2) + rg;  // C/D: row=(lane>>4)*4+reg
                    const int cj  = w*32 + jf*16 + lm;             //      col=lane&15
                    const int pc  = ((((cj >> 2) ^ ((row >> 3) & 7)) << 2) | (cj & 3));
                    M1[row * K + pc] = acc1[mf][jf][rg];
                    M2[row * K + pc] = acc2[mf][jf][rg];
                }
        __syncthreads();

        // ---- stage 2 (round-1 verified fp32 path): r1 = C12*M1 - M2*C12, etc. ----
        const int tx = tid & 15, ty = tid >> 4;
        const int r0 = ty * 8;
        const int ca = tx * 4, cb = 64 + tx * 4;
        const int kcol = ty & 7;
        const float* c12 = C12g + (size_t)n * K * K;
        const float* c21 = C21g + (size_t)n * K * K;
        v4f acc1a[8], acc1b[8], acc2a[8], acc2b[8];
        #pragma unroll
        for (int i = 0; i < 8; ++i) {
            acc1a[i] = (v4f){0,0,0,0}; acc1b[i] = (v4f){0,0,0,0};
            acc2a[i] = (v4f){0,0,0,0}; acc2b[i] = (v4f){0,0,0,0};
        }
        for (int j = 0; j < K; ++j) {
            const int keyj = (j >> 3) & 7;
            const int ga = (tx ^ keyj) << 2;
            const int gb = ((16 + tx) ^ keyj) << 2;
            const v4f m1ra = *(const v4f*)(M1 + j * K + ga);
            const v4f m1rb = *(const v4f*)(M1 + j * K + gb);
            const v4f m2ra = *(const v4f*)(M2 + j * K + ga);
            const v4f m2rb = *(const v4f*)(M2 + j * K + gb);
            const v4f c12ra = *(const v4f*)(c12 + j * K + ca);
            const v4f c12rb = *(const v4f*)(c12 + j * K + cb);
            const v4f c21ra = *(const v4f*)(c21 + j * K + ca);
            const v4f c21rb = *(const v4f*)(c21 + j * K + cb);
            const int jp = (((j >> 2) ^ kcol) << 2) | (j & 3);
            #pragma unroll
            for (int i = 0; i < 8; ++i) {
                const int r = r0 + i;
                const float x12 = c12[r * K + j];
                const float x21 = c21[r * K + j];
                const float m1c = M1[r * K + jp];
                const float m2c = M2[r * K + jp];
                acc1a[i] += m1ra * x12; acc1a[i] -= c12ra * m2c;
                acc1b[i] += m1rb * x12; acc1b[i] -= c12rb * m2c;
                acc2a[i] += m2ra * x21; acc2a[i] -= c21ra * m1c;
                acc2b[i] += m2rb * x21; acc2b[i] -= c21rb * m1c;
            }
        }
        float s = 0.0f;
        #pragma unroll
        for (int i = 0; i < 8; ++i)
            #pragma unroll
            for (int e = 0; e < 4; ++e) {
                s += acc1a[i][e] * acc1a[i][e] + acc1b[i][e] * acc1b[i][e];
                s += acc2a[i][e] * acc2a[i][e] + acc2b[i][e] * acc2b[i][e];
            }
        #pragma unroll
        for (int off = 32; off; off >>= 1) s += __shfl_down(s, off, 64);
        if ((tid & 63) == 0)
            atomicAdd(out + 3, s * (W_PRE / (float)(N * K * K)));
    } else {
        // --------------------------- small losses path ---------------------------
        float* lds = (float*)smem;
        const int idx = b - nPre;
        const int n = idx >> 2, p = idx & 3;
        const float* c12 = C12g + (size_t)n * K * K;
        const float* c21 = C21g + (size_t)n * K * K;
        const float* Xg = (p == 1 || p == 3) ? c21 : c12;
        const float* Yg = (p == 0) ? c21 : c12;
        const float* ea = (p == 0) ? ev1g + n * K : ev2g + n * K;
        const float* eb = (p == 0) ? ev2g + n * K : ev1g + n * K;
        float* X = lds;             // [K][129]
        float* Y = lds + K * 129;
        const int tx = tid & 15, ty = tid >> 4;
        float lap = 0.0f;
        for (int i = tid; i < K * K / 4; i += 256) {
            const int r = i >> 5, c4 = (i & 31) * 4;
            const v4f x = *(const v4f*)(Xg + r * K + c4);
            X[r * 129 + c4 + 0] = x[0]; X[r * 129 + c4 + 1] = x[1];
            X[r * 129 + c4 + 2] = x[2]; X[r * 129 + c4 + 3] = x[3];
            if (p < 2) {
                const v4f y = *(const v4f*)(Yg + r * K + c4);
                Y[r * 129 + c4 + 0] = y[0]; Y[r * 129 + c4 + 1] = y[1];
                Y[r * 129 + c4 + 2] = y[2]; Y[r * 129 + c4 + 3] = y[3];
                const float ebi = eb[r];
                #pragma unroll
                for (int e = 0; e < 4; ++e) {
                    const float dlt = ea[c4 + e] - ebi;
                    lap += x[e] * x[e] * dlt * dlt;
                }
            }
        }
        __syncthreads();
        const int i0 = ty * 8, k0 = tx * 8;
        float z[8][8];
        #pragma unroll
        for (int i = 0; i < 8; ++i)
            #pragma unroll
            for (int t = 0; t < 8; ++t) z[i][t] = 0.0f;
        for (int j = 0; j < K; ++j) {
            float xi[8], yk[8];
            if (p < 2) {   // Z = X @ Y
                #pragma unroll
                for (int i = 0; i < 8; ++i) xi[i] = X[(i0 + i) * 129 + j];
                #pragma unroll
                for (int t = 0; t < 8; ++t) yk[t] = Y[j * 129 + k0 + t];
            } else {       // Z = X^T @ X
                #pragma unroll
                for (int i = 0; i < 8; ++i) xi[i] = X[j * 129 + i0 + i];
                #pragma unroll
                for (int t = 0; t < 8; ++t) yk[t] = X[j * 129 + k0 + t];
            }
            #pragma unroll
            for (int i = 0; i < 8; ++i)
                #pragma unroll
                for (int t = 0; t < 8; ++t) z[i][t] += xi[i] * yk[t];
        }
        float s = 0.0f;
        #pragma unroll
        for (int i = 0; i < 8; ++i)
            #pragma unroll
            for (int t = 0; t < 8; ++t) {
                const float e = z[i][t] - ((i0 + i) == (k0 + t) ? 1.0f : 0.0f);
                s += e * e;
            }
        #pragma unroll
        for (int off = 32; off; off >>= 1) {
            s   += __shfl_down(s, off, 64);
            lap += __shfl_down(lap, off, 64);
        }
        if ((tid & 63) == 0) {
            if (p < 2) {
                atomicAdd(out + 0, s * (W_BIJ / (float)N));
                atomicAdd(out + 2, lap * (W_LAP / (float)N));
            } else {
                atomicAdd(out + 1, s * (W_ORTH / (float)N));
            }
        }
    }
}

extern "C" void kernel_launch(void* const* d_in, const int* in_sizes, int n_in,
                              void* d_out, int out_size, void* d_ws, size_t ws_size,
                              hipStream_t stream) {
    (void)n_in; (void)d_ws; (void)ws_size;
    const float* C12 = (const float*)d_in[0];
    const float* C21 = (const float*)d_in[1];
    const float* F1  = (const float*)d_in[2];
    const float* F2  = (const float*)d_in[3];
    const float* E1  = (const float*)d_in[4];
    const float* E2  = (const float*)d_in[5];
    const float* T1  = (const float*)d_in[6];
    const float* T2  = (const float*)d_in[7];
    const float* ev1 = (const float*)d_in[8];
    const float* ev2 = (const float*)d_in[9];
    const int* desc  = (const int*)d_in[10];
    float* out = (float*)d_out;

    const int N  = in_sizes[8] / K;            // evals_1: N*K
    const int ND = in_sizes[10];               // desc_ind
    const int V  = in_sizes[4] / (N * K);      // evecs_1: N*V*K
    const int CF = in_sizes[2] / (N * V);      // feat_1: N*V*C

    const size_t shmem = (size_t)(2 * K * 129) * sizeof(float);  // 132096 B
    hipFuncSetAttribute((const void*)surfm_fused,
                        hipFuncAttributeMaxDynamicSharedMemorySize, (int)shmem);
    hipMemsetAsync(d_out, 0, (size_t)out_size * sizeof(float), stream);

    const int blocks = N * ND + 4 * N;
    surfm_fused<<<blocks, 256, shmem, stream>>>(C12, C21, F1, F2, E1, E2, T1, T2,
                                                ev1, ev2, desc, out, N, ND, V, CF);
}

// Round 3
// 360.925 us; speedup vs baseline: 4.2291x; 2.2026x over previous
//
#include <hip/hip_runtime.h>

typedef float v4f __attribute__((ext_vector_type(4)));
typedef unsigned int u32;
typedef __attribute__((ext_vector_type(4))) u32 u32x4;
typedef __attribute__((ext_vector_type(8))) short bhalf8;   // 8 bf16 in 4 VGPRs

#define K 128
#define W_BIJ 1000.0f
#define W_ORTH 1000.0f
#define W_LAP 1.0f
#define W_PRE 100000.0f

#define NCH 79          // ceil(5000/64) V-chunks of 64
#define SPLIT 5
#define TILE_B 16384    // one A chunk-tile: 128 rows x 64 k x bf16
#define MSLOT 32768     // one (n,d) M-pair: 2 * 128*128 floats

static __device__ __forceinline__ unsigned short f2b(float x) {
    union { float f; unsigned int u; } v; v.f = x;
    unsigned int u = v.u + 0x7FFFu + ((v.u >> 16) & 1u);   // RNE
    return (unsigned short)(u >> 16);
}
static __device__ __forceinline__ u32 pk2(float lo, float hi) {
    return (u32)f2b(lo) | ((u32)f2b(hi) << 16);
}
static __device__ __forceinline__ void gload_lds16(const void* g, void* l) {
    __builtin_amdgcn_global_load_lds((const __attribute__((address_space(1))) u32*)g,
                                     (__attribute__((address_space(3))) u32*)l, 16, 0, 0);
}

// ============================ kernel0: convert A ============================
// T[mat][n] (K x V fp32) -> Abf tiles [mat*8+n][c] of 128x64 bf16, PRE-SWIZZLED:
// tile byte (r*128 + grp*16) holds logical k-group (grp ^ (r&7)) of chunk c,
// so a linear global_load_lds lands the image that MFMA frag reads expect
// (read addr = (r*128 + k*2) ^ ((r&7)<<4)). Chunk 78 zero-padded past V.
extern "C" __global__ __launch_bounds__(256, 4)
void surfm_convA(const float* __restrict__ T1, const float* __restrict__ T2,
                 unsigned short* __restrict__ Abf, int V)
{
    const int blk = blockIdx.x;            // (mat*8+n)*NCH + c
    const int c  = blk % NCH;
    const int mn = blk / NCH;              // mat*8+n
    const float* src = ((mn & 8) ? T2 : T1) + (size_t)(mn & 7) * K * V;
    char* dst = (char*)(Abf) + (size_t)blk * TILE_B;
    #pragma unroll
    for (int it = 0; it < 4; ++it) {
        const int item = it * 256 + threadIdx.x;   // 1024 = 128 r x 8 grp
        const int grp = item & 7, r = item >> 3;
        const int kg = grp ^ (r & 7);
        const int k = c * 64 + kg * 8;
        u32x4 o = (u32x4){0u,0u,0u,0u};
        if (k + 8 <= V) {
            const v4f lo = *(const v4f*)(src + (size_t)r * V + k);
            const v4f hi = *(const v4f*)(src + (size_t)r * V + k + 4);
            o[0] = pk2(lo[0], lo[1]); o[1] = pk2(lo[2], lo[3]);
            o[2] = pk2(hi[0], hi[1]); o[3] = pk2(hi[2], hi[3]);
        }
        *(u32x4*)(dst + r * 128 + grp * 16) = o;
    }
}

// ============================ kernel1: stage 1 ==============================
// 1000 blocks: b -> n = b&7 (XCD affinity), rem = b>>3, d = rem/5, s = rem%5.
// Block accumulates M1,M2 over chunks c = s, s+5, ... (VC=64), then stores
// partials (partStride>0) or atomicAdds (partStride==0) into Mout.
extern "C" __global__ __launch_bounds__(256, 2)
void surfm_stage1(const float* __restrict__ E1g, const float* __restrict__ E2g,
                  const float* __restrict__ F1, const float* __restrict__ F2,
                  const unsigned short* __restrict__ Abf,
                  const int* __restrict__ desc, float* __restrict__ Mout,
                  int V, int CF, int partStride)
{
    __shared__ char smem[65536];
    char* As1 = smem;                  // 128 x 64 bf16, swz (r&7)<<4  (16KB)
    char* As2 = smem + 16384;
    char* Bt1 = smem + 32768;          // 128 j x 64 v bf16, swz ((j&7)^((j>>3)&7))<<4
    char* Bt2 = smem + 49152;

    const int tid = threadIdx.x;
    const int b = blockIdx.x;
    const int n = b & 7;
    const int rem = b >> 3;
    const int d = rem / SPLIT;
    const int s = rem - d * SPLIT;
    const int col = desc[d];

    const float* B1g = E1g + (size_t)n * V * K;
    const float* B2g = E2g + (size_t)n * V * K;
    const float* F1w = F1 + (size_t)n * V * CF + col;
    const float* F2w = F2 + (size_t)n * V * CF + col;
    const char* A1t = (const char*)Abf + (size_t)n * NCH * TILE_B;
    const char* A2t = (const char*)Abf + (size_t)(8 + n) * NCH * TILE_B;

    const int l  = tid & 63;
    const int w  = tid >> 6;
    const int wq = __builtin_amdgcn_readfirstlane(w);
    const int lm = l & 15;
    const int lk = (l >> 4) * 8;

    // precomputed LDS byte offsets for MFMA frags
    const int keyR = (lm & 7) << 4;
    int aOff[2];                         // A: + mf*2048
    #pragma unroll
    for (int ks = 0; ks < 2; ++ks) aOff[ks] = lm * 128 + ((ks * 64 + lk * 2) ^ keyR);
    const int jA = w * 32 + lm, jB = jA + 16;
    const int keyA = (((jA & 7) ^ ((jA >> 3) & 7)) << 4);
    const int keyB = (((jB & 7) ^ ((jB >> 3) & 7)) << 4);
    int bOffA[2], bOffB[2];
    #pragma unroll
    for (int ks = 0; ks < 2; ++ks) {
        bOffA[ks] = jA * 128 + ((ks * 64 + lk * 2) ^ keyA);
        bOffB[ks] = jB * 128 + ((ks * 64 + lk * 2) ^ keyB);
    }

    v4f acc1[8][2], acc2[8][2];
    #pragma unroll
    for (int mf = 0; mf < 8; ++mf)
        #pragma unroll
        for (int jf = 0; jf < 2; ++jf) {
            acc1[mf][jf] = (v4f){0.f,0.f,0.f,0.f};
            acc2[mf][jf] = (v4f){0.f,0.f,0.f,0.f};
        }

    for (int c = s; c < NCH; c += SPLIT) {
        __syncthreads();
        // ---- A: direct global->LDS (pre-swizzled tiles, zero-padded) ----
        {
            const char* t1 = A1t + (size_t)c * TILE_B;
            const char* t2 = A2t + (size_t)c * TILE_B;
            #pragma unroll
            for (int i4 = 0; i4 < 4; ++i4) {
                const int base = (i4 * 4 + wq) * 1024;
                gload_lds16(t1 + base + l * 16, As1 + base);
                gload_lds16(t2 + base + l * 16, As2 + base);
            }
        }
        // ---- B: load E fp32, fold w, convert, swizzled scatter ----
        const int v0 = c * 64;
        #pragma unroll
        for (int it = 0; it < 4; ++it) {
            const int i  = it * 256 + tid;       // 1024 = 32 j4 x 32 vp
            const int j4 = (i & 31) * 4;
            const int vp = (i >> 5) * 2;
            const int va = v0 + vp, vb = va + 1;
            v4f e1a = {0.f,0.f,0.f,0.f}, e1b = e1a, e2a = e1a, e2b = e1a;
            if (va < V) {
                const float w1 = F1w[(size_t)va * CF];
                const float w2 = F2w[(size_t)va * CF];
                e1a = *(const v4f*)(B1g + (size_t)va * K + j4) * w1;
                e2a = *(const v4f*)(B2g + (size_t)va * K + j4) * w2;
            }
            if (vb < V) {
                const float w1 = F1w[(size_t)vb * CF];
                const float w2 = F2w[(size_t)vb * CF];
                e1b = *(const v4f*)(B1g + (size_t)vb * K + j4) * w1;
                e2b = *(const v4f*)(B2g + (size_t)vb * K + j4) * w2;
            }
            #pragma unroll
            for (int e = 0; e < 4; ++e) {
                const int j = j4 + e;
                const int key = (((j & 7) ^ ((j >> 3) & 7)) << 4);
                const int byte = (j * 128 + vp * 2) ^ key;
                *(u32*)(Bt1 + byte) = pk2(e1a[e], e1b[e]);
                *(u32*)(Bt2 + byte) = pk2(e2a[e], e2b[e]);
            }
        }
        __syncthreads();
        // ---- MFMA over this chunk (k = 64) ----
        #pragma unroll
        for (int ks = 0; ks < 2; ++ks) {
            const bhalf8 bB1a = *(const bhalf8*)(Bt1 + bOffA[ks]);
            const bhalf8 bB1b = *(const bhalf8*)(Bt1 + bOffB[ks]);
            const bhalf8 bB2a = *(const bhalf8*)(Bt2 + bOffA[ks]);
            const bhalf8 bB2b = *(const bhalf8*)(Bt2 + bOffB[ks]);
            #pragma unroll
            for (int mf = 0; mf < 8; ++mf) {
                const bhalf8 a1 = *(const bhalf8*)(As1 + mf * 2048 + aOff[ks]);
                const bhalf8 a2 = *(const bhalf8*)(As2 + mf * 2048 + aOff[ks]);
                acc1[mf][0] = __builtin_amdgcn_mfma_f32_16x16x32_bf16(a1, bB1a, acc1[mf][0], 0, 0, 0);
                acc1[mf][1] = __builtin_amdgcn_mfma_f32_16x16x32_bf16(a1, bB1b, acc1[mf][1], 0, 0, 0);
                acc2[mf][0] = __builtin_amdgcn_mfma_f32_16x16x32_bf16(a2, bB2a, acc2[mf][0], 0, 0, 0);
                acc2[mf][1] = __builtin_amdgcn_mfma_f32_16x16x32_bf16(a2, bB2b, acc2[mf][1], 0, 0, 0);
            }
        }
    }

    // ---- write out M partials ----
    const int slot = (partStride ? s * partStride : 0) + n * 25 + d;
    float* d1 = Mout + (size_t)slot * MSLOT;
    float* d2 = d1 + 16384;
    #pragma unroll
    for (int mf = 0; mf < 8; ++mf)
        #pragma unroll
        for (int jf = 0; jf < 2; ++jf) {
            const int coln = w * 32 + jf * 16 + lm;
            #pragma unroll
            for (int rg = 0; rg < 4; ++rg) {
                const int row = mf * 16 + (l >> 4) * 4 + rg;
                const int off = row * K + coln;
                if (partStride) {
                    d1[off] = acc1[mf][jf][rg];
                    d2[off] = acc2[mf][jf][rg];
                } else {
                    atomicAdd(d1 + off, acc1[mf][jf][rg]);
                    atomicAdd(d2 + off, acc2[mf][jf][rg]);
                }
            }
        }
}

// ============================ kernel2: stage 2 ==============================
// blocks [0,200): sum M partials -> LDS [128][132], fp32 residual GEMMs, l_pre.
// blocks [200,232): small losses (bij/orth/lap), verified round-1/2 code.
extern "C" __global__ __launch_bounds__(256, 1)
void surfm_stage2(const float* __restrict__ C12g, const float* __restrict__ C21g,
                  const float* __restrict__ ev1g, const float* __restrict__ ev2g,
                  const float* __restrict__ Mws, int nPart, int partStride,
                  float* __restrict__ out, int N, int ND)
{
    extern __shared__ float lds[];
    const int b = blockIdx.x;
    const int tid = threadIdx.x;
    const int nPre = N * ND;
    const int tx = tid & 15, ty = tid >> 4;

    if (b < nPre) {
        const int n = b & 7, d = b >> 3;
        const int slot = n * 25 + d;
        float* M1p = lds;                 // [128][132]
        float* M2p = lds + 128 * 132;
        for (int i = tid; i < 8192; i += 256) {       // v4f granules, 2 mats
            const int mat = i >> 12;
            const int rc4 = (i & 4095) * 4;
            v4f a = (v4f){0.f,0.f,0.f,0.f};
            for (int ss = 0; ss < nPart; ++ss)
                a += *(const v4f*)(Mws + ((size_t)(ss * partStride + slot) * 2 + mat) * 16384 + rc4);
            const int r = rc4 >> 7, cc = rc4 & 127;
            float* dst = (mat ? M2p : M1p) + r * 132 + cc;
            dst[0] = a[0]; dst[1] = a[1]; dst[2] = a[2]; dst[3] = a[3];
        }
        __syncthreads();

        const float* c12 = C12g + (size_t)n * K * K;
        const float* c21 = C21g + (size_t)n * K * K;
        const int r0 = ty * 8;
        const int ca = tx * 4, cb = 64 + tx * 4;
        v4f a1a[8], a1b[8], a2a[8], a2b[8];
        #pragma unroll
        for (int i = 0; i < 8; ++i) {
            a1a[i] = (v4f){0,0,0,0}; a1b[i] = (v4f){0,0,0,0};
            a2a[i] = (v4f){0,0,0,0}; a2b[i] = (v4f){0,0,0,0};
        }
        for (int j = 0; j < K; ++j) {
            const v4f m1ra = *(const v4f*)(M1p + j * 132 + ca);
            const v4f m1rb = *(const v4f*)(M1p + j * 132 + cb);
            const v4f m2ra = *(const v4f*)(M2p + j * 132 + ca);
            const v4f m2rb = *(const v4f*)(M2p + j * 132 + cb);
            const v4f c12ra = *(const v4f*)(c12 + j * K + ca);
            const v4f c12rb = *(const v4f*)(c12 + j * K + cb);
            const v4f c21ra = *(const v4f*)(c21 + j * K + ca);
            const v4f c21rb = *(const v4f*)(c21 + j * K + cb);
            #pragma unroll
            for (int i = 0; i < 8; ++i) {
                const int r = r0 + i;
                const float x12 = c12[r * K + j];
                const float x21 = c21[r * K + j];
                const float m1c = M1p[r * 132 + j];
                const float m2c = M2p[r * 132 + j];
                a1a[i] += m1ra * x12; a1a[i] -= c12ra * m2c;
                a1b[i] += m1rb * x12; a1b[i] -= c12rb * m2c;
                a2a[i] += m2ra * x21; a2a[i] -= c21ra * m1c;
                a2b[i] += m2rb * x21; a2b[i] -= c21rb * m1c;
            }
        }
        float sacc = 0.0f;
        #pragma unroll
        for (int i = 0; i < 8; ++i)
            #pragma unroll
            for (int e = 0; e < 4; ++e) {
                sacc += a1a[i][e] * a1a[i][e] + a1b[i][e] * a1b[i][e];
                sacc += a2a[i][e] * a2a[i][e] + a2b[i][e] * a2b[i][e];
            }
        #pragma unroll
        for (int off = 32; off; off >>= 1) sacc += __shfl_down(sacc, off, 64);
        if ((tid & 63) == 0)
            atomicAdd(out + 3, sacc * (W_PRE / (float)(N * K * K)));
    } else {
        const int idx = b - nPre;
        const int n = idx >> 2, p = idx & 3;
        const float* c12 = C12g + (size_t)n * K * K;
        const float* c21 = C21g + (size_t)n * K * K;
        const float* Xg = (p == 1 || p == 3) ? c21 : c12;
        const float* Yg = (p == 0) ? c21 : c12;
        const float* ea = (p == 0) ? ev1g + n * K : ev2g + n * K;
        const float* eb = (p == 0) ? ev2g + n * K : ev1g + n * K;
        float* X = lds;             // [K][129]
        float* Y = lds + K * 129;
        float lap = 0.0f;
        for (int i = tid; i < K * K / 4; i += 256) {
            const int r = i >> 5, c4 = (i & 31) * 4;
            const v4f x = *(const v4f*)(Xg + r * K + c4);
            X[r * 129 + c4 + 0] = x[0]; X[r * 129 + c4 + 1] = x[1];
            X[r * 129 + c4 + 2] = x[2]; X[r * 129 + c4 + 3] = x[3];
            if (p < 2) {
                const v4f y = *(const v4f*)(Yg + r * K + c4);
                Y[r * 129 + c4 + 0] = y[0]; Y[r * 129 + c4 + 1] = y[1];
                Y[r * 129 + c4 + 2] = y[2]; Y[r * 129 + c4 + 3] = y[3];
                const float ebi = eb[r];
                #pragma unroll
                for (int e = 0; e < 4; ++e) {
                    const float dlt = ea[c4 + e] - ebi;
                    lap += x[e] * x[e] * dlt * dlt;
                }
            }
        }
        __syncthreads();
        const int i0 = ty * 8, k0 = tx * 8;
        float z[8][8];
        #pragma unroll
        for (int i = 0; i < 8; ++i)
            #pragma unroll
            for (int t = 0; t < 8; ++t) z[i][t] = 0.0f;
        for (int j = 0; j < K; ++j) {
            float xi[8], yk[8];
            if (p < 2) {
                #pragma unroll
                for (int i = 0; i < 8; ++i) xi[i] = X[(i0 + i) * 129 + j];
                #pragma unroll
                for (int t = 0; t < 8; ++t) yk[t] = Y[j * 129 + k0 + t];
            } else {
                #pragma unroll
                for (int i = 0; i < 8; ++i) xi[i] = X[j * 129 + i0 + i];
                #pragma unroll
                for (int t = 0; t < 8; ++t) yk[t] = X[j * 129 + k0 + t];
            }
            #pragma unroll
            for (int i = 0; i < 8; ++i)
                #pragma unroll
                for (int t = 0; t < 8; ++t) z[i][t] += xi[i] * yk[t];
        }
        float sacc = 0.0f;
        #pragma unroll
        for (int i = 0; i < 8; ++i)
            #pragma unroll
            for (int t = 0; t < 8; ++t) {
                const float e = z[i][t] - ((i0 + i) == (k0 + t) ? 1.0f : 0.0f);
                sacc += e * e;
            }
        #pragma unroll
        for (int off = 32; off; off >>= 1) {
            sacc += __shfl_down(sacc, off, 64);
            lap  += __shfl_down(lap, off, 64);
        }
        if ((tid & 63) == 0) {
            if (p < 2) {
                atomicAdd(out + 0, sacc * (W_BIJ / (float)N));
                atomicAdd(out + 2, lap * (W_LAP / (float)N));
            } else {
                atomicAdd(out + 1, sacc * (W_ORTH / (float)N));
            }
        }
    }
}

// ================= fallback: round-2 verified fused kernel =================
extern "C" __global__ __launch_bounds__(256, 1)
void surfm_fused(const float* __restrict__ C12g, const float* __restrict__ C21g,
                 const float* __restrict__ F1, const float* __restrict__ F2,
                 const float* __restrict__ E1g, const float* __restrict__ E2g,
                 const float* __restrict__ T1, const float* __restrict__ T2,
                 const float* __restrict__ ev1g, const float* __restrict__ ev2g,
                 const int* __restrict__ desc, float* __restrict__ out,
                 int N, int ND, int V, int CF)
{
    extern __shared__ char smem[];
    const int b   = blockIdx.x;
    const int tid = threadIdx.x;
    const int nPre = N * ND;

    if (b < nPre) {
        const int n = b & 7;
        const int d = b >> 3;
        const int col = desc[d];
        const float* A1g = T1 + (size_t)n * K * V;
        const float* A2g = T2 + (size_t)n * K * V;
        const float* B1g = E1g + (size_t)n * V * K;
        const float* B2g = E2g + (size_t)n * V * K;
        const float* w1g = F1 + (size_t)n * V * CF;
        const float* w2g = F2 + (size_t)n * V * CF;

        char* As1 = smem;
        char* As2 = smem + 32768;
        char* Bt1 = smem + 65536;
        char* Bt2 = smem + 98304;

        const int l  = tid & 63;
        const int w  = tid >> 6;
        const int lm = l & 15;
        const int lk = (l >> 4) * 8;

        v4f acc1[8][2], acc2[8][2];
        #pragma unroll
        for (int mf = 0; mf < 8; ++mf)
            #pragma unroll
            for (int jf = 0; jf < 2; ++jf) {
                acc1[mf][jf] = (v4f){0.f,0.f,0.f,0.f};
                acc2[mf][jf] = (v4f){0.f,0.f,0.f,0.f};
            }

        for (int v0 = 0; v0 < V; v0 += 128) {
            __syncthreads();
            #pragma unroll 4
            for (int it = 0; it < 16; ++it) {
                const int i  = it * 256 + tid;
                const int r  = i >> 5;
                const int c4 = (i & 31) * 4;
                const int vg = v0 + c4;
                v4f a1 = {0.f,0.f,0.f,0.f}, a2 = {0.f,0.f,0.f,0.f};
                if (vg < V) {
                    a1 = *(const v4f*)(A1g + (size_t)r * V + vg);
                    a2 = *(const v4f*)(A2g + (size_t)r * V + vg);
                }
                const int byte = (r * 256 + c4 * 2) ^ ((r & 7) << 4);
                short4 p1, p2;
                p1.x = (short)f2b(a1[0]); p1.y = (short)f2b(a1[1]);
                p1.z = (short)f2b(a1[2]); p1.w = (short)f2b(a1[3]);
                p2.x = (short)f2b(a2[0]); p2.y = (short)f2b(a2[1]);
                p2.z = (short)f2b(a2[2]); p2.w = (short)f2b(a2[3]);
                *(short4*)(As1 + byte) = p1;
                *(short4*)(As2 + byte) = p2;
            }
            #pragma unroll 2
            for (int it = 0; it < 8; ++it) {
                const int i  = it * 256 + tid;
                const int j4 = (i & 31) * 4;
                const int vp = (i >> 5) * 2;
                const int va = v0 + vp, vb = va + 1;
                v4f e1a = {0.f,0.f,0.f,0.f}, e1b = e1a, e2a = e1a, e2b = e1a;
                if (va < V) {
                    const float w1 = w1g[(size_t)va * CF + col];
                    const float w2 = w2g[(size_t)va * CF + col];
                    e1a = *(const v4f*)(B1g + (size_t)va * K + j4) * w1;
                    e2a = *(const v4f*)(B2g + (size_t)va * K + j4) * w2;
                }
                if (vb < V) {
                    const float w1 = w1g[(size_t)vb * CF + col];
                    const float w2 = w2g[(size_t)vb * CF + col];
                    e1b = *(const v4f*)(B1g + (size_t)vb * K + j4) * w1;
                    e2b = *(const v4f*)(B2g + (size_t)vb * K + j4) * w2;
                }
                #pragma unroll
                for (int e = 0; e < 4; ++e) {
                    const int j = j4 + e;
                    const int key = (((j & 7) ^ ((j >> 3) & 7)) << 4);
                    const int byte = (j * 256 + vp * 2) ^ key;
                    *(u32*)(Bt1 + byte) = pk2(e1a[e], e1b[e]);
                    *(u32*)(Bt2 + byte) = pk2(e2a[e], e2b[e]);
                }
            }
            __syncthreads();
            #pragma unroll
            for (int ks = 0; ks < 4; ++ks) {
                const int k0 = ks * 32 + lk;
                bhalf8 bB1[2], bB2[2];
                #pragma unroll
                for (int jf = 0; jf < 2; ++jf) {
                    const int j = w * 32 + jf * 16 + lm;
                    const int key = (((j & 7) ^ ((j >> 3) & 7)) << 4);
                    const int byte = (j * 256 + k0 * 2) ^ key;
                    bB1[jf] = *(const bhalf8*)(Bt1 + byte);
                    bB2[jf] = *(const bhalf8*)(Bt2 + byte);
                }
                #pragma unroll
                for (int mf = 0; mf < 8; ++mf) {
                    const int r = mf * 16 + lm;
                    const int byte = (r * 256 + k0 * 2) ^ ((r & 7) << 4);
                    const bhalf8 a1 = *(const bhalf8*)(As1 + byte);
                    const bhalf8 a2 = *(const bhalf8*)(As2 + byte);
                    acc1[mf][0] = __builtin_amdgcn_mfma_f32_16x16x32_bf16(a1, bB1[0], acc1[mf][0], 0, 0, 0);
                    acc1[mf][1] = __builtin_amdgcn_mfma_f32_16x16x32_bf16(a1, bB1[1], acc1[mf][1], 0, 0, 0);
                    acc2[mf][0] = __builtin_amdgcn_mfma_f32_16x16x32_bf16(a2, bB2[0], acc2[mf][0], 0, 0, 0);
                    acc2[mf][1] = __builtin_amdgcn_mfma_f32_16x16x32_bf16(a2, bB2[1], acc2[mf][1], 0, 0, 0);
                }
            }
        }
        __syncthreads();
        float* M1 = (float*)smem;
        float* M2 = (float*)smem + K * K;
        #pragma unroll
        for (int mf = 0; mf < 8; ++mf)
            #pragma unroll
            for (int jf = 0; jf < 2; ++jf)
                #pragma unroll
                for (int rg = 0; rg < 4; ++rg) {
                    const int row = mf * 16 + ((l >> 4) << 2) + rg;
                    const int cj  = w * 32 + jf * 16 + lm;
                    const int pc  = ((((cj >> 2) ^ ((row >> 3) & 7)) << 2) | (cj & 3));
                    M1[row * K + pc] = acc1[mf][jf][rg];
                    M2[row * K + pc] = acc2[mf][jf][rg];
                }
        __syncthreads();

        const int tx = tid & 15, ty = tid >> 4;
        const int r0 = ty * 8;
        const int ca = tx * 4, cb = 64 + tx * 4;
        const int kcol = ty & 7;
        const float* c12 = C12g + (size_t)n * K * K;
        const float* c21 = C21g + (size_t)n * K * K;
        v4f acc1a[8], acc1b[8], acc2a[8], acc2b[8];
        #pragma unroll
        for (int i = 0; i < 8; ++i) {
            acc1a[i] = (v4f){0,0,0,0}; acc1b[i] = (v4f){0,0,0,0};
            acc2a[i] = (v4f){0,0,0,0}; acc2b[i] = (v4f){0,0,0,0};
        }
        for (int j = 0; j < K; ++j) {
            const int keyj = (j >> 3) & 7;
            const int ga = (tx ^ keyj) << 2;
            const int gb = ((16 + tx) ^ keyj) << 2;
            const v4f m1ra = *(const v4f*)(M1 + j * K + ga);
            const v4f m1rb = *(const v4f*)(M1 + j * K + gb);
            const v4f m2ra = *(const v4f*)(M2 + j * K + ga);
            const v4f m2rb = *(const v4f*)(M2 + j * K + gb);
            const v4f c12ra = *(const v4f*)(c12 + j * K + ca);
            const v4f c12rb = *(const v4f*)(c12 + j * K + cb);
            const v4f c21ra = *(const v4f*)(c21 + j * K + ca);
            const v4f c21rb = *(const v4f*)(c21 + j * K + cb);
            const int jp = (((j >> 2) ^ kcol) << 2) | (j & 3);
            #pragma unroll
            for (int i = 0; i < 8; ++i) {
                const int r = r0 + i;
                const float x12 = c12[r * K + j];
                const float x21 = c21[r * K + j];
                const float m1c = M1[r * K + jp];
                const float m2c = M2[r * K + jp];
                acc1a[i] += m1ra * x12; acc1a[i] -= c12ra * m2c;
                acc1b[i] += m1rb * x12; acc1b[i] -= c12rb * m2c;
                acc2a[i] += m2ra * x21; acc2a[i] -= c21ra * m1c;
                acc2b[i] += m2rb * x21; acc2b[i] -= c21rb * m1c;
            }
        }
        float s = 0.0f;
        #pragma unroll
        for (int i = 0; i < 8; ++i)
            #pragma unroll
            for (int e = 0; e < 4; ++e) {
                s += acc1a[i][e] * acc1a[i][e] + acc1b[i][e] * acc1b[i][e];
                s += acc2a[i][e] * acc2a[i][e] + acc2b[i][e] * acc2b[i][e];
            }
        #pragma unroll
        for (int off = 32; off; off >>= 1) s += __shfl_down(s, off, 64);
        if ((tid & 63) == 0)
            atomicAdd(out + 3, s * (W_PRE / (float)(N * K * K)));
    } else {
        float* ldsf = (float*)smem;
        const int idx = b - nPre;
        const int n = idx >> 2, p = idx & 3;
        const float* c12 = C12g + (size_t)n * K * K;
        const float* c21 = C21g + (size_t)n * K * K;
        const float* Xg = (p == 1 || p == 3) ? c21 : c12;
        const float* Yg = (p == 0) ? c21 : c12;
        const float* ea = (p == 0) ? ev1g + n * K : ev2g + n * K;
        const float* eb = (p == 0) ? ev2g + n * K : ev1g + n * K;
        float* X = ldsf;
        float* Y = ldsf + K * 129;
        const int tx = tid & 15, ty = tid >> 4;
        float lap = 0.0f;
        for (int i = tid; i < K * K / 4; i += 256) {
            const int r = i >> 5, c4 = (i & 31) * 4;
            const v4f x = *(const v4f*)(Xg + r * K + c4);
            X[r * 129 + c4 + 0] = x[0]; X[r * 129 + c4 + 1] = x[1];
            X[r * 129 + c4 + 2] = x[2]; X[r * 129 + c4 + 3] = x[3];
            if (p < 2) {
                const v4f y = *(const v4f*)(Yg + r * K + c4);
                Y[r * 129 + c4 + 0] = y[0]; Y[r * 129 + c4 + 1] = y[1];
                Y[r * 129 + c4 + 2] = y[2]; Y[r * 129 + c4 + 3] = y[3];
                const float ebi = eb[r];
                #pragma unroll
                for (int e = 0; e < 4; ++e) {
                    const float dlt = ea[c4 + e] - ebi;
                    lap += x[e] * x[e] * dlt * dlt;
                }
            }
        }
        __syncthreads();
        const int i0 = ty * 8, k0 = tx * 8;
        float z[8][8];
        #pragma unroll
        for (int i = 0; i < 8; ++i)
            #pragma unroll
            for (int t = 0; t < 8; ++t) z[i][t] = 0.0f;
        for (int j = 0; j < K; ++j) {
            float xi[8], yk[8];
            if (p < 2) {
                #pragma unroll
                for (int i = 0; i < 8; ++i) xi[i] = X[(i0 + i) * 129 + j];
                #pragma unroll
                for (int t = 0; t < 8; ++t) yk[t] = Y[j * 129 + k0 + t];
            } else {
                #pragma unroll
                for (int i = 0; i < 8; ++i) xi[i] = X[j * 129 + i0 + i];
                #pragma unroll
                for (int t = 0; t < 8; ++t) yk[t] = X[j * 129 + k0 + t];
            }
            #pragma unroll
            for (int i = 0; i < 8; ++i)
                #pragma unroll
                for (int t = 0; t < 8; ++t) z[i][t] += xi[i] * yk[t];
        }
        float s = 0.0f;
        #pragma unroll
        for (int i = 0; i < 8; ++i)
            #pragma unroll
            for (int t = 0; t < 8; ++t) {
                const float e = z[i][t] - ((i0 + i) == (k0 + t) ? 1.0f : 0.0f);
                s += e * e;
            }
        #pragma unroll
        for (int off = 32; off; off >>= 1) {
            s   += __shfl_down(s, off, 64);
            lap += __shfl_down(lap, off, 64);
        }
        if ((tid & 63) == 0) {
            if (p < 2) {
                atomicAdd(out + 0, s * (W_BIJ / (float)N));
                atomicAdd(out + 2, lap * (W_LAP / (float)N));
            } else {
                atomicAdd(out + 1, s * (W_ORTH / (float)N));
            }
        }
    }
}

extern "C" void kernel_launch(void* const* d_in, const int* in_sizes, int n_in,
                              void* d_out, int out_size, void* d_ws, size_t ws_size,
                              hipStream_t stream) {
    (void)n_in;
    const float* C12 = (const float*)d_in[0];
    const float* C21 = (const float*)d_in[1];
    const float* F1  = (const float*)d_in[2];
    const float* F2  = (const float*)d_in[3];
    const float* E1  = (const float*)d_in[4];
    const float* E2  = (const float*)d_in[5];
    const float* T1  = (const float*)d_in[6];
    const float* T2  = (const float*)d_in[7];
    const float* ev1 = (const float*)d_in[8];
    const float* ev2 = (const float*)d_in[9];
    const int* desc  = (const int*)d_in[10];
    float* out = (float*)d_out;

    const int N  = in_sizes[8] / K;            // evals_1: N*K
    const int ND = in_sizes[10];               // desc_ind
    const int V  = in_sizes[4] / (N * K);      // evecs_1: N*V*K
    const int CF = in_sizes[2] / (N * V);      // feat_1: N*V*C

    hipMemsetAsync(d_out, 0, (size_t)out_size * sizeof(float), stream);

    const bool okShape = (N == 8 && ND == 25 && V == 5000 && CF == 128);
    const size_t AbfBytes   = (size_t)2 * 8 * NCH * TILE_B;          // 20.7 MB
    const size_t MsetBytes  = (size_t)200 * MSLOT * sizeof(float);   // 26.2 MB
    const size_t needPart   = AbfBytes + SPLIT * MsetBytes;          // 151.8 MB
    const size_t needAtomic = AbfBytes + MsetBytes;                  // 46.9 MB

    int mode = 0;
    if (okShape && ws_size >= needPart) mode = 2;
    else if (okShape && ws_size >= needAtomic) mode = 1;

    if (mode == 0) {
        const size_t shmem = (size_t)(2 * K * 129) * sizeof(float);  // 132096
        hipFuncSetAttribute((const void*)surfm_fused,
                            hipFuncAttributeMaxDynamicSharedMemorySize, (int)shmem);
        const int blocks = N * ND + 4 * N;
        surfm_fused<<<blocks, 256, shmem, stream>>>(C12, C21, F1, F2, E1, E2, T1, T2,
                                                    ev1, ev2, desc, out, N, ND, V, CF);
        return;
    }

    unsigned short* Abf = (unsigned short*)d_ws;
    float* Mws = (float*)((char*)d_ws + AbfBytes);

    surfm_convA<<<2 * 8 * NCH, 256, 0, stream>>>(T1, T2, Abf, V);
    if (mode == 1)
        hipMemsetAsync(Mws, 0, MsetBytes, stream);
    surfm_stage1<<<8 * 25 * SPLIT, 256, 0, stream>>>(E1, E2, F1, F2, Abf, desc, Mws,
                                                     V, CF, (mode == 2) ? 200 : 0);
    const size_t shmem2 = (size_t)(2 * 128 * 132) * sizeof(float);   // 135168
    hipFuncSetAttribute((const void*)surfm_stage2,
                        hipFuncAttributeMaxDynamicSharedMemorySize, (int)shmem2);
    surfm_stage2<<<N * ND + 4 * N, 256, shmem2, stream>>>(C12, C21, ev1, ev2, Mws,
                                                          (mode == 2) ? SPLIT : 1, 200,
                                                          out, N, ND);
}

// Round 4
// 201.426 us; speedup vs baseline: 7.5780x; 1.7918x over previous
//
#include <hip/hip_runtime.h>

typedef float v4f __attribute__((ext_vector_type(4)));
typedef unsigned int u32;
typedef __attribute__((ext_vector_type(4))) u32 u32x4;
typedef __attribute__((ext_vector_type(8))) short bhalf8;

#define K 128
#define W_BIJ 1000.0f
#define W_ORTH 1000.0f
#define W_LAP 1.0f
#define W_PRE 100000.0f

#define NCH 79          // ceil(5000/64) V-chunks of 64
#define TILE_B 16384    // 128 rows x 64 k bf16 tile
#define CTILE_B 32768   // 128 x 128 bf16 tile
#define VPAD 5056       // NCH*64

union B8 { u32x4 u; bhalf8 h; };

static __device__ __forceinline__ unsigned short f2b(float x) {
    union { float f; unsigned int u; } v; v.f = x;
    unsigned int u = v.u + 0x7FFFu + ((v.u >> 16) & 1u);   // RNE
    return (unsigned short)(u >> 16);
}
static __device__ __forceinline__ u32 pk2(float lo, float hi) {
    return (u32)f2b(lo) | ((u32)f2b(hi) << 16);
}
static __device__ __forceinline__ float bitsf(u32 x) {
    union { u32 u; float f; } v; v.u = x; return v.f;
}
static __device__ __forceinline__ u32 cvtpk(float lo, float hi) {
    u32 r; asm("v_cvt_pk_bf16_f32 %0, %1, %2" : "=v"(r) : "v"(lo), "v"(hi)); return r;
}
static __device__ __forceinline__ void gload_lds16(const void* g, void* l) {
    __builtin_amdgcn_global_load_lds((const __attribute__((address_space(1))) u32*)g,
                                     (__attribute__((address_space(3))) u32*)l, 16, 0, 0);
}

// ============================= conv kernel ==================================
// blocks [0,1264):      Abf tiles  (T1/T2 -> pre-swizzled 128x64 bf16)
// blocks [1264,2528):   Ebf tiles  (E1/E2 -> transposed [j][v] pre-swizzled bf16)
// blocks [2528,2928):   Fbf        (feat column gather -> fp32 [mat][n][d][VPAD])
// blocks [2928,2944):   Cbf        (C12/C21 -> n-layout + t-layout bf16 tiles)
extern "C" __global__ __launch_bounds__(256, 2)
void surfm_conv(const float* __restrict__ T1, const float* __restrict__ T2,
                const float* __restrict__ E1, const float* __restrict__ E2,
                const float* __restrict__ F1, const float* __restrict__ F2,
                const float* __restrict__ C12g, const float* __restrict__ C21g,
                const int* __restrict__ desc,
                unsigned short* __restrict__ Abf, unsigned short* __restrict__ Ebf,
                float* __restrict__ Fbf, char* __restrict__ Cbf,
                int V, int CF)
{
    __shared__ char csm[32768];
    const int b = blockIdx.x;
    const int tid = threadIdx.x;

    if (b < 1264) {
        // ---------------- Abf: [mn][c] tiles, logical (r, k) pre-swizzled ----
        const int c  = b % NCH;
        const int mn = b / NCH;
        const float* src = ((mn & 8) ? T2 : T1) + (size_t)(mn & 7) * K * V;
        char* dst = (char*)Abf + (size_t)b * TILE_B;
        #pragma unroll
        for (int it = 0; it < 4; ++it) {
            const int item = it * 256 + tid;         // 1024 = 128 r x 8 grp
            const int grp = item & 7, r = item >> 3;
            const int kg = grp ^ (r & 7);
            const int k = c * 64 + kg * 8;
            u32x4 o = (u32x4){0u,0u,0u,0u};
            if (k + 8 <= V) {
                const v4f lo = *(const v4f*)(src + (size_t)r * V + k);
                const v4f hi = *(const v4f*)(src + (size_t)r * V + k + 4);
                o[0] = pk2(lo[0], lo[1]); o[1] = pk2(lo[2], lo[3]);
                o[2] = pk2(hi[0], hi[1]); o[3] = pk2(hi[2], hi[3]);
            }
            *(u32x4*)(dst + r * 128 + grp * 16) = o;
        }
    } else if (b < 2528) {
        // ---------------- Ebf: transposed tiles [j=128][v=64] ----------------
        const int idx = b - 1264;
        const int c  = idx % NCH;
        const int mn = idx / NCH;
        const float* src = ((mn & 8) ? E2 : E1) + (size_t)(mn & 7) * V * K;
        char* dst = (char*)Ebf + (size_t)idx * TILE_B;
        // phase 1: coalesced read rows v, scatter bf16 pairs into LDS tile
        #pragma unroll
        for (int it = 0; it < 8; ++it) {
            const int item = it * 256 + tid;          // 2048 = 32 vp x 32 j4
            const int vp = item >> 5;                 // v-pair 0..31
            const int j4 = (item & 31) * 4;
            const int v = c * 64 + vp * 2;
            v4f e0 = {0.f,0.f,0.f,0.f}, e1 = e0;
            if (v < V)     e0 = *(const v4f*)(src + (size_t)v * K + j4);
            if (v + 1 < V) e1 = *(const v4f*)(src + (size_t)(v + 1) * K + j4);
            #pragma unroll
            for (int e = 0; e < 4; ++e) {
                const int j = j4 + e;
                *(u32*)(csm + j * 128 + ((vp * 4) ^ ((j & 7) << 4))) = pk2(e0[e], e1[e]);
            }
        }
        __syncthreads();
        // phase 2: linear dump (tile is gload_lds-ready)
        #pragma unroll
        for (int it = 0; it < 4; ++it) {
            const int item = it * 256 + tid;
            *(u32x4*)(dst + item * 16) = *(const u32x4*)(csm + item * 16);
        }
    } else if (b < 2928) {
        // ---------------- Fbf: w[v] = feat[n][v][desc[d]] fp32, padded -------
        const int idx = b - 2528;                     // mn*25 + d
        const int d  = idx % 25;
        const int mn = idx / 25;
        const int col = desc[d];
        const float* src = ((mn & 8) ? F2 : F1) + (size_t)(mn & 7) * V * CF + col;
        float* dst = Fbf + (size_t)idx * VPAD;
        for (int i = tid; i < VPAD; i += 256)
            dst[i] = (i < V) ? src[(size_t)i * CF] : 0.0f;
    } else {
        // ---------------- Cbf: n-layout + t-layout 128x128 bf16 tiles --------
        const int idx = b - 2928;                     // mat*8 + n
        const float* src = ((idx & 8) ? C21g : C12g) + (size_t)(idx & 7) * K * K;
        char* outN = Cbf + (size_t)(idx * 2 + 0) * CTILE_B;
        char* outT = Cbf + (size_t)(idx * 2 + 1) * CTILE_B;
        // n-layout: direct
        #pragma unroll
        for (int it = 0; it < 8; ++it) {
            const int item = it * 256 + tid;          // 2048 = 128 r x 16 grp
            const int r = item >> 4, grp = item & 15;
            const int g = grp ^ (r & 7);
            const v4f lo = *(const v4f*)(src + r * K + g * 8);
            const v4f hi = *(const v4f*)(src + r * K + g * 8 + 4);
            u32x4 o;
            o[0] = pk2(lo[0], lo[1]); o[1] = pk2(lo[2], lo[3]);
            o[2] = pk2(hi[0], hi[1]); o[3] = pk2(hi[2], hi[3]);
            *(u32x4*)(outN + r * 256 + grp * 16) = o;
        }
        // t-layout: LDS transpose (row pairs -> u32 scatter), then linear dump
        #pragma unroll
        for (int it = 0; it < 8; ++it) {
            const int item = it * 256 + tid;          // 2048 = 64 rp x 32 j4
            const int rp = item >> 5;                 // row pair 0..63
            const int j4 = (item & 31) * 4;
            const v4f r0 = *(const v4f*)(src + (2 * rp) * K + j4);
            const v4f r1 = *(const v4f*)(src + (2 * rp + 1) * K + j4);
            #pragma unroll
            for (int e = 0; e < 4; ++e) {
                const int j = j4 + e;
                *(u32*)(csm + j * 256 + ((rp * 4) ^ ((j & 7) << 4))) = pk2(r0[e], r1[e]);
            }
        }
        __syncthreads();
        #pragma unroll
        for (int it = 0; it < 8; ++it) {
            const int item = it * 256 + tid;
            *(u32x4*)(outT + item * 16) = *(const u32x4*)(csm + item * 16);
        }
    }
}

// ============================= stage 1 ======================================
// 208 blocks x 512 threads: b -> n = b&7 (XCD), mat = (b>>3)&1, dgi = b>>4.
// Each block: M[d0], M[d0+1] (one mat) = A(128xV) * diag(w_d) * E(VxK),
// counted-vmcnt double-buffered gload_lds pipeline, w folded on B-frags.
// Epilogue writes Mbf n-layout + t-layout pre-swizzled bf16 tiles.
extern "C" __global__ __launch_bounds__(512, 2)
void surfm_stage1(const char* __restrict__ Abf, const char* __restrict__ Ebf,
                  const float* __restrict__ Fbf, char* __restrict__ Mbf)
{
    extern __shared__ char sm[];
    // LDS: A dbuf [0,32768), E dbuf [32768,65536), w fp32 [65536, 65536+40960)
    const int tid = threadIdx.x;
    const int l  = tid & 63;
    const int wv = tid >> 6;
    const int wq = __builtin_amdgcn_readfirstlane(wv);
    const int b = blockIdx.x;
    const int n = b & 7;
    const int rest = b >> 3;            // 0..25
    const int mat = rest & 1;
    const int dgi = rest >> 1;          // 0..12
    const int d0 = dgi * 2;
    const bool hasD1 = (d0 + 1) < 25;

    const int mn = mat * 8 + n;
    const char* gA = Abf + (size_t)mn * NCH * TILE_B;
    const char* gE = Ebf + (size_t)mn * NCH * TILE_B;
    const char* gW = (const char*)(Fbf + ((size_t)mn * 25 + d0) * VPAD);

    // staging role: waves 0-3 stage A quarters, 4-7 stage E quarters
    const int stile = wq >> 2;
    const int squad = wq & 3;
    const char* gsrc0 = stile ? gE : gA;
    char* lb0 = sm + stile * 32768;

    // compute role: wave-tile 64 rows x 32 cols
    const int wm = wq >> 2, wj = wq & 3;
    const int moff = wm * 64, joff = wj * 32;
    const int lm = l & 15;
    const int lk = (l >> 4) * 8;

    v4f acc[2][4][2];
    #pragma unroll
    for (int dd = 0; dd < 2; ++dd)
        #pragma unroll
        for (int mf = 0; mf < 4; ++mf)
            #pragma unroll
            for (int jf = 0; jf < 2; ++jf)
                acc[dd][mf][jf] = (v4f){0.f,0.f,0.f,0.f};

    // prologue: w (2 consecutive d-slices, 40448B) + chunk0
    for (int i = wq; i < 40; i += 8)
        gload_lds16(gW + i * 1024 + l * 16, sm + 65536 + i * 1024);
    {
        const char* gs = gsrc0 + squad * 4096 + l * 16;
        char* ld = lb0 + squad * 4096;
        #pragma unroll
        for (int i = 0; i < 4; ++i)
            gload_lds16(gs + i * 1024, ld + i * 1024);
    }
    asm volatile("s_waitcnt vmcnt(0)" ::: "memory");
    __builtin_amdgcn_s_barrier();

    #pragma unroll 1
    for (int c = 0; c < NCH; ++c) {
        const int par = c & 1;
        if (c + 1 < NCH) {
            const char* gs = gsrc0 + (size_t)(c + 1) * TILE_B + squad * 4096 + l * 16;
            char* ld = lb0 + (par ^ 1) * 16384 + squad * 4096;
            #pragma unroll
            for (int i = 0; i < 4; ++i)
                gload_lds16(gs + i * 1024, ld + i * 1024);
            asm volatile("s_waitcnt vmcnt(4)" ::: "memory");
        } else {
            asm volatile("s_waitcnt vmcnt(0)" ::: "memory");
        }
        __builtin_amdgcn_s_barrier();
        __builtin_amdgcn_sched_barrier(0);

        const char* Ab = sm + par * 16384;
        const char* Eb = sm + 32768 + par * 16384;
        #pragma unroll
        for (int ks = 0; ks < 2; ++ks) {
            const int kb = ks * 64 + lk * 2;
            const float* pw0 = (const float*)(sm + 65536 + c * 256 + ks * 128) + lk;
            const float* pw1 = (const float*)(sm + 65536 + 20224 + c * 256 + ks * 128) + lk;
            const v4f w0a = *(const v4f*)pw0, w0b = *(const v4f*)(pw0 + 4);
            const v4f w1a = *(const v4f*)pw1, w1b = *(const v4f*)(pw1 + 4);
            const float wl0[4] = {w0a[0], w0a[2], w0b[0], w0b[2]};
            const float wh0[4] = {w0a[1], w0a[3], w0b[1], w0b[3]};
            const float wl1[4] = {w1a[0], w1a[2], w1b[0], w1b[2]};
            const float wh1[4] = {w1a[1], w1a[3], w1b[1], w1b[3]};
            B8 p0[2], p1[2];
            #pragma unroll
            for (int jf = 0; jf < 2; ++jf) {
                const int j = joff + jf * 16 + lm;
                const u32x4 e = *(const u32x4*)(Eb + j * 128 + (kb ^ ((j & 7) << 4)));
                #pragma unroll
                for (int t = 0; t < 4; ++t) {
                    const float elo = bitsf(e[t] << 16);
                    const float ehi = bitsf(e[t] & 0xFFFF0000u);
                    p0[jf].u[t] = cvtpk(elo * wl0[t], ehi * wh0[t]);
                    p1[jf].u[t] = cvtpk(elo * wl1[t], ehi * wh1[t]);
                }
            }
            #pragma unroll
            for (int mf = 0; mf < 4; ++mf) {
                const int r = moff + mf * 16 + lm;
                B8 a; a.u = *(const u32x4*)(Ab + r * 128 + (kb ^ ((r & 7) << 4)));
                #pragma unroll
                for (int jf = 0; jf < 2; ++jf) {
                    acc[0][mf][jf] = __builtin_amdgcn_mfma_f32_16x16x32_bf16(a.h, p0[jf].h, acc[0][mf][jf], 0, 0, 0);
                    acc[1][mf][jf] = __builtin_amdgcn_mfma_f32_16x16x32_bf16(a.h, p1[jf].h, acc[1][mf][jf], 0, 0, 0);
                }
            }
        }
        __builtin_amdgcn_s_barrier();
    }

    // epilogue: per valid d, dump acc -> LDS fp32 -> bf16 n & t tiles
    float* ML = (float*)sm;                // [128][132]
    #pragma unroll 1
    for (int dd = 0; dd < 2; ++dd) {
        if (dd == 1 && !hasD1) break;
        __syncthreads();
        #pragma unroll
        for (int mf = 0; mf < 4; ++mf)
            #pragma unroll
            for (int jf = 0; jf < 2; ++jf)
                #pragma unroll
                for (int rg = 0; rg < 4; ++rg) {
                    const int row = moff + mf * 16 + (l >> 4) * 4 + rg;
                    const int col = joff + jf * 16 + lm;
                    ML[row * 132 + col] = acc[dd][mf][jf][rg];
                }
        __syncthreads();
        const int dcur = d0 + dd;
        char* outN = Mbf + (size_t)((n * 25 + dcur) * 2 + mat) * 65536;
        char* outT = outN + 32768;
        #pragma unroll
        for (int it = 0; it < 8; ++it) {
            const int item = it * 512 + tid;          // 4096 = 2 lay x 2048 grp
            const int lay = item >> 11;
            const int g2 = item & 2047;
            const int r = g2 >> 4, grp = g2 & 15;
            const int g = grp ^ (r & 7);
            u32x4 o;
            if (lay == 0) {
                const float* p = ML + r * 132 + g * 8;
                const v4f a = *(const v4f*)p, bq = *(const v4f*)(p + 4);
                o[0] = pk2(a[0], a[1]);  o[1] = pk2(a[2], a[3]);
                o[2] = pk2(bq[0], bq[1]); o[3] = pk2(bq[2], bq[3]);
                *(u32x4*)(outN + r * 256 + grp * 16) = o;
            } else {
                const float* p = ML + (g * 8) * 132 + r;
                o[0] = pk2(p[0],   p[132]); o[1] = pk2(p[264], p[396]);
                o[2] = pk2(p[528], p[660]); o[3] = pk2(p[792], p[924]);
                *(u32x4*)(outT + r * 256 + grp * 16) = o;
            }
        }
    }
}

// ============================= stage 2 ======================================
// blocks [0,200): l_pre residual GEMMs via MFMA from pre-built bf16 tiles.
// blocks [200,232): small losses (bij/orth/lap), verified fp32 path.
extern "C" __global__ __launch_bounds__(256, 1)
void surfm_stage2(const float* __restrict__ C12g, const float* __restrict__ C21g,
                  const float* __restrict__ ev1g, const float* __restrict__ ev2g,
                  const char* __restrict__ Cbf, const char* __restrict__ Mbf,
                  float* __restrict__ out, int N, int ND)
{
    extern __shared__ char sm[];
    const int b = blockIdx.x;
    const int tid = threadIdx.x;
    const int nPre = N * ND;

    if (b < nPre) {
        const int n = b & 7, d = b >> 3;
        const size_t slot = n * 25 + d;
        const int l = tid & 63;
        const int wq = __builtin_amdgcn_readfirstlane(tid >> 6);
        const int lm = l & 15, lk = (l >> 4) * 8;
        const int wm = wq >> 1, wj = wq & 1;
        float rsum = 0.0f;

        #pragma unroll 1
        for (int ph = 0; ph < 2; ++ph) {
            // phase tiles: T0=A_s (C n), T1=B_s (M t), T2=A_t (M n), T3=B_t (C t)
            const char* s0 = Cbf + ((size_t)(ph * 8 + n) * 2 + 0) * CTILE_B;
            const char* s1 = Mbf + (slot * 2 + (ph ? 1 : 0)) * 65536 + 32768;
            const char* s2 = Mbf + (slot * 2 + (ph ? 0 : 1)) * 65536;
            const char* s3 = Cbf + ((size_t)(ph * 8 + n) * 2 + 1) * CTILE_B;
            const char* gs = (wq == 0) ? s0 : (wq == 1) ? s1 : (wq == 2) ? s2 : s3;
            char* ld = sm + wq * 32768;
            if (ph) __builtin_amdgcn_s_barrier();     // prev compute done
            #pragma unroll
            for (int i = 0; i < 32; ++i)
                gload_lds16(gs + i * 1024 + l * 16, ld + i * 1024);
            asm volatile("s_waitcnt vmcnt(0)" ::: "memory");
            __builtin_amdgcn_s_barrier();
            __builtin_amdgcn_sched_barrier(0);

            v4f as_[4][4], at_[4][4];
            #pragma unroll
            for (int mf = 0; mf < 4; ++mf)
                #pragma unroll
                for (int jf = 0; jf < 4; ++jf) {
                    as_[mf][jf] = (v4f){0.f,0.f,0.f,0.f};
                    at_[mf][jf] = (v4f){0.f,0.f,0.f,0.f};
                }
            #pragma unroll
            for (int ks = 0; ks < 4; ++ks) {
                const int kb = ks * 64 + lk * 2;
                B8 bS[4], bT[4];
                #pragma unroll
                for (int jf = 0; jf < 4; ++jf) {
                    const int j = wj * 64 + jf * 16 + lm;
                    const int off = j * 256 + (kb ^ ((j & 7) << 4));
                    bS[jf].u = *(const u32x4*)(sm + 32768 + off);
                    bT[jf].u = *(const u32x4*)(sm + 98304 + off);
                }
                #pragma unroll
                for (int mf = 0; mf < 4; ++mf) {
                    const int r = wm * 64 + mf * 16 + lm;
                    const int off = r * 256 + (kb ^ ((r & 7) << 4));
                    B8 aS; aS.u = *(const u32x4*)(sm + off);
                    B8 aT; aT.u = *(const u32x4*)(sm + 65536 + off);
                    #pragma unroll
                    for (int jf = 0; jf < 4; ++jf) {
                        as_[mf][jf] = __builtin_amdgcn_mfma_f32_16x16x32_bf16(aS.h, bS[jf].h, as_[mf][jf], 0, 0, 0);
                        at_[mf][jf] = __builtin_amdgcn_mfma_f32_16x16x32_bf16(aT.h, bT[jf].h, at_[mf][jf], 0, 0, 0);
                    }
                }
            }
            #pragma unroll
            for (int mf = 0; mf < 4; ++mf)
                #pragma unroll
                for (int jf = 0; jf < 4; ++jf) {
                    const v4f df = as_[mf][jf] - at_[mf][jf];
                    rsum += df[0]*df[0] + df[1]*df[1] + df[2]*df[2] + df[3]*df[3];
                }
        }
        #pragma unroll
        for (int off = 32; off; off >>= 1) rsum += __shfl_down(rsum, off, 64);
        if (l == 0)
            atomicAdd(out + 3, rsum * (W_PRE / (float)(N * K * K)));
    } else {
        // --------------------------- small losses ---------------------------
        float* lds = (float*)sm;
        const int idx = b - nPre;
        const int n = idx >> 2, p = idx & 3;
        const float* c12 = C12g + (size_t)n * K * K;
        const float* c21 = C21g + (size_t)n * K * K;
        const float* Xg = (p == 1 || p == 3) ? c21 : c12;
        const float* Yg = (p == 0) ? c21 : c12;
        const float* ea = (p == 0) ? ev1g + n * K : ev2g + n * K;
        const float* eb = (p == 0) ? ev2g + n * K : ev1g + n * K;
        float* X = lds;             // [K][129]
        float* Y = lds + K * 129;
        const int tx = tid & 15, ty = tid >> 4;
        float lap = 0.0f;
        for (int i = tid; i < K * K / 4; i += 256) {
            const int r = i >> 5, c4 = (i & 31) * 4;
            const v4f x = *(const v4f*)(Xg + r * K + c4);
            X[r * 129 + c4 + 0] = x[0]; X[r * 129 + c4 + 1] = x[1];
            X[r * 129 + c4 + 2] = x[2]; X[r * 129 + c4 + 3] = x[3];
            if (p < 2) {
                const v4f y = *(const v4f*)(Yg + r * K + c4);
                Y[r * 129 + c4 + 0] = y[0]; Y[r * 129 + c4 + 1] = y[1];
                Y[r * 129 + c4 + 2] = y[2]; Y[r * 129 + c4 + 3] = y[3];
                const float ebi = eb[r];
                #pragma unroll
                for (int e = 0; e < 4; ++e) {
                    const float dlt = ea[c4 + e] - ebi;
                    lap += x[e] * x[e] * dlt * dlt;
                }
            }
        }
        __syncthreads();
        const int i0 = ty * 8, k0 = tx * 8;
        float z[8][8];
        #pragma unroll
        for (int i = 0; i < 8; ++i)
            #pragma unroll
            for (int t = 0; t < 8; ++t) z[i][t] = 0.0f;
        for (int j = 0; j < K; ++j) {
            float xi[8], yk[8];
            if (p < 2) {
                #pragma unroll
                for (int i = 0; i < 8; ++i) xi[i] = X[(i0 + i) * 129 + j];
                #pragma unroll
                for (int t = 0; t < 8; ++t) yk[t] = Y[j * 129 + k0 + t];
            } else {
                #pragma unroll
                for (int i = 0; i < 8; ++i) xi[i] = X[j * 129 + i0 + i];
                #pragma unroll
                for (int t = 0; t < 8; ++t) yk[t] = X[j * 129 + k0 + t];
            }
            #pragma unroll
            for (int i = 0; i < 8; ++i)
                #pragma unroll
                for (int t = 0; t < 8; ++t) z[i][t] += xi[i] * yk[t];
        }
        float sacc = 0.0f;
        #pragma unroll
        for (int i = 0; i < 8; ++i)
            #pragma unroll
            for (int t = 0; t < 8; ++t) {
                const float e = z[i][t] - ((i0 + i) == (k0 + t) ? 1.0f : 0.0f);
                sacc += e * e;
            }
        #pragma unroll
        for (int off = 32; off; off >>= 1) {
            sacc += __shfl_down(sacc, off, 64);
            lap  += __shfl_down(lap, off, 64);
        }
        if ((tid & 63) == 0) {
            if (p < 2) {
                atomicAdd(out + 0, sacc * (W_BIJ / (float)N));
                atomicAdd(out + 2, lap * (W_LAP / (float)N));
            } else {
                atomicAdd(out + 1, sacc * (W_ORTH / (float)N));
            }
        }
    }
}

// ================= fallback: round-2 verified fused kernel =================
extern "C" __global__ __launch_bounds__(256, 1)
void surfm_fused(const float* __restrict__ C12g, const float* __restrict__ C21g,
                 const float* __restrict__ F1, const float* __restrict__ F2,
                 const float* __restrict__ E1g, const float* __restrict__ E2g,
                 const float* __restrict__ T1, const float* __restrict__ T2,
                 const float* __restrict__ ev1g, const float* __restrict__ ev2g,
                 const int* __restrict__ desc, float* __restrict__ out,
                 int N, int ND, int V, int CF)
{
    extern __shared__ char smem[];
    const int b   = blockIdx.x;
    const int tid = threadIdx.x;
    const int nPre = N * ND;

    if (b < nPre) {
        const int n = b & 7;
        const int d = b >> 3;
        const int col = desc[d];
        const float* A1g = T1 + (size_t)n * K * V;
        const float* A2g = T2 + (size_t)n * K * V;
        const float* B1g = E1g + (size_t)n * V * K;
        const float* B2g = E2g + (size_t)n * V * K;
        const float* w1g = F1 + (size_t)n * V * CF;
        const float* w2g = F2 + (size_t)n * V * CF;

        char* As1 = smem;
        char* As2 = smem + 32768;
        char* Bt1 = smem + 65536;
        char* Bt2 = smem + 98304;

        const int l  = tid & 63;
        const int w  = tid >> 6;
        const int lm = l & 15;
        const int lk = (l >> 4) * 8;

        v4f acc1[8][2], acc2[8][2];
        #pragma unroll
        for (int mf = 0; mf < 8; ++mf)
            #pragma unroll
            for (int jf = 0; jf < 2; ++jf) {
                acc1[mf][jf] = (v4f){0.f,0.f,0.f,0.f};
                acc2[mf][jf] = (v4f){0.f,0.f,0.f,0.f};
            }

        for (int v0 = 0; v0 < V; v0 += 128) {
            __syncthreads();
            #pragma unroll 4
            for (int it = 0; it < 16; ++it) {
                const int i  = it * 256 + tid;
                const int r  = i >> 5;
                const int c4 = (i & 31) * 4;
                const int vg = v0 + c4;
                v4f a1 = {0.f,0.f,0.f,0.f}, a2 = {0.f,0.f,0.f,0.f};
                if (vg < V) {
                    a1 = *(const v4f*)(A1g + (size_t)r * V + vg);
                    a2 = *(const v4f*)(A2g + (size_t)r * V + vg);
                }
                const int byte = (r * 256 + c4 * 2) ^ ((r & 7) << 4);
                short4 p1, p2;
                p1.x = (short)f2b(a1[0]); p1.y = (short)f2b(a1[1]);
                p1.z = (short)f2b(a1[2]); p1.w = (short)f2b(a1[3]);
                p2.x = (short)f2b(a2[0]); p2.y = (short)f2b(a2[1]);
                p2.z = (short)f2b(a2[2]); p2.w = (short)f2b(a2[3]);
                *(short4*)(As1 + byte) = p1;
                *(short4*)(As2 + byte) = p2;
            }
            #pragma unroll 2
            for (int it = 0; it < 8; ++it) {
                const int i  = it * 256 + tid;
                const int j4 = (i & 31) * 4;
                const int vp = (i >> 5) * 2;
                const int va = v0 + vp, vb = va + 1;
                v4f e1a = {0.f,0.f,0.f,0.f}, e1b = e1a, e2a = e1a, e2b = e1a;
                if (va < V) {
                    const float w1 = w1g[(size_t)va * CF + col];
                    const float w2 = w2g[(size_t)va * CF + col];
                    e1a = *(const v4f*)(B1g + (size_t)va * K + j4) * w1;
                    e2a = *(const v4f*)(B2g + (size_t)va * K + j4) * w2;
                }
                if (vb < V) {
                    const float w1 = w1g[(size_t)vb * CF + col];
                    const float w2 = w2g[(size_t)vb * CF + col];
                    e1b = *(const v4f*)(B1g + (size_t)vb * K + j4) * w1;
                    e2b = *(const v4f*)(B2g + (size_t)vb * K + j4) * w2;
                }
                #pragma unroll
                for (int e = 0; e < 4; ++e) {
                    const int j = j4 + e;
                    const int key = (((j & 7) ^ ((j >> 3) & 7)) << 4);
                    const int byte = (j * 256 + vp * 2) ^ key;
                    *(u32*)(Bt1 + byte) = pk2(e1a[e], e1b[e]);
                    *(u32*)(Bt2 + byte) = pk2(e2a[e], e2b[e]);
                }
            }
            __syncthreads();
            #pragma unroll
            for (int ks = 0; ks < 4; ++ks) {
                const int k0 = ks * 32 + lk;
                bhalf8 bB1[2], bB2[2];
                #pragma unroll
                for (int jf = 0; jf < 2; ++jf) {
                    const int j = w * 32 + jf * 16 + lm;
                    const int key = (((j & 7) ^ ((j >> 3) & 7)) << 4);
                    const int byte = (j * 256 + k0 * 2) ^ key;
                    bB1[jf] = *(const bhalf8*)(Bt1 + byte);
                    bB2[jf] = *(const bhalf8*)(Bt2 + byte);
                }
                #pragma unroll
                for (int mf = 0; mf < 8; ++mf) {
                    const int r = mf * 16 + lm;
                    const int byte = (r * 256 + k0 * 2) ^ ((r & 7) << 4);
                    const bhalf8 a1 = *(const bhalf8*)(As1 + byte);
                    const bhalf8 a2 = *(const bhalf8*)(As2 + byte);
                    acc1[mf][0] = __builtin_amdgcn_mfma_f32_16x16x32_bf16(a1, bB1[0], acc1[mf][0], 0, 0, 0);
                    acc1[mf][1] = __builtin_amdgcn_mfma_f32_16x16x32_bf16(a1, bB1[1], acc1[mf][1], 0, 0, 0);
                    acc2[mf][0] = __builtin_amdgcn_mfma_f32_16x16x32_bf16(a2, bB2[0], acc2[mf][0], 0, 0, 0);
                    acc2[mf][1] = __builtin_amdgcn_mfma_f32_16x16x32_bf16(a2, bB2[1], acc2[mf][1], 0, 0, 0);
                }
            }
        }
        __syncthreads();
        float* M1 = (float*)smem;
        float* M2 = (float*)smem + K * K;
        #pragma unroll
        for (int mf = 0; mf < 8; ++mf)
            #pragma unroll
            for (int jf = 0; jf < 2; ++jf)
                #pragma unroll
                for (int rg = 0; rg < 4; ++rg) {
                    const int row = mf * 16 + ((l >> 4) << 2) + rg;
                    const int cj  = w * 32 + jf * 16 + lm;
                    const int pc  = ((((cj >> 2) ^ ((row >> 3) & 7)) << 2) | (cj & 3));
                    M1[row * K + pc] = acc1[mf][jf][rg];
                    M2[row * K + pc] = acc2[mf][jf][rg];
                }
        __syncthreads();

        const int tx = tid & 15, ty = tid >> 4;
        const int r0 = ty * 8;
        const int ca = tx * 4, cb = 64 + tx * 4;
        const int kcol = ty & 7;
        const float* c12 = C12g + (size_t)n * K * K;
        const float* c21 = C21g + (size_t)n * K * K;
        v4f acc1a[8], acc1b[8], acc2a[8], acc2b[8];
        #pragma unroll
        for (int i = 0; i < 8; ++i) {
            acc1a[i] = (v4f){0,0,0,0}; acc1b[i] = (v4f){0,0,0,0};
            acc2a[i] = (v4f){0,0,0,0}; acc2b[i] = (v4f){0,0,0,0};
        }
        for (int j = 0; j < K; ++j) {
            const int keyj = (j >> 3) & 7;
            const int ga = (tx ^ keyj) << 2;
            const int gb = ((16 + tx) ^ keyj) << 2;
            const v4f m1ra = *(const v4f*)(M1 + j * K + ga);
            const v4f m1rb = *(const v4f*)(M1 + j * K + gb);
            const v4f m2ra = *(const v4f*)(M2 + j * K + ga);
            const v4f m2rb = *(const v4f*)(M2 + j * K + gb);
            const v4f c12ra = *(const v4f*)(c12 + j * K + ca);
            const v4f c12rb = *(const v4f*)(c12 + j * K + cb);
            const v4f c21ra = *(const v4f*)(c21 + j * K + ca);
            const v4f c21rb = *(const v4f*)(c21 + j * K + cb);
            const int jp = (((j >> 2) ^ kcol) << 2) | (j & 3);
            #pragma unroll
            for (int i = 0; i < 8; ++i) {
                const int r = r0 + i;
                const float x12 = c12[r * K + j];
                const float x21 = c21[r * K + j];
                const float m1c = M1[r * K + jp];
                const float m2c = M2[r * K + jp];
                acc1a[i] += m1ra * x12; acc1a[i] -= c12ra * m2c;
                acc1b[i] += m1rb * x12; acc1b[i] -= c12rb * m2c;
                acc2a[i] += m2ra * x21; acc2a[i] -= c21ra * m1c;
                acc2b[i] += m2rb * x21; acc2b[i] -= c21rb * m1c;
            }
        }
        float s = 0.0f;
        #pragma unroll
        for (int i = 0; i < 8; ++i)
            #pragma unroll
            for (int e = 0; e < 4; ++e) {
                s += acc1a[i][e] * acc1a[i][e] + acc1b[i][e] * acc1b[i][e];
                s += acc2a[i][e] * acc2a[i][e] + acc2b[i][e] * acc2b[i][e];
            }
        #pragma unroll
        for (int off = 32; off; off >>= 1) s += __shfl_down(s, off, 64);
        if ((tid & 63) == 0)
            atomicAdd(out + 3, s * (W_PRE / (float)(N * K * K)));
    } else {
        float* ldsf = (float*)smem;
        const int idx = b - nPre;
        const int n = idx >> 2, p = idx & 3;
        const float* c12 = C12g + (size_t)n * K * K;
        const float* c21 = C21g + (size_t)n * K * K;
        const float* Xg = (p == 1 || p == 3) ? c21 : c12;
        const float* Yg = (p == 0) ? c21 : c12;
        const float* ea = (p == 0) ? ev1g + n * K : ev2g + n * K;
        const float* eb = (p == 0) ? ev2g + n * K : ev1g + n * K;
        float* X = ldsf;
        float* Y = ldsf + K * 129;
        const int tx = tid & 15, ty = tid >> 4;
        float lap = 0.0f;
        for (int i = tid; i < K * K / 4; i += 256) {
            const int r = i >> 5, c4 = (i & 31) * 4;
            const v4f x = *(const v4f*)(Xg + r * K + c4);
            X[r * 129 + c4 + 0] = x[0]; X[r * 129 + c4 + 1] = x[1];
            X[r * 129 + c4 + 2] = x[2]; X[r * 129 + c4 + 3] = x[3];
            if (p < 2) {
                const v4f y = *(const v4f*)(Yg + r * K + c4);
                Y[r * 129 + c4 + 0] = y[0]; Y[r * 129 + c4 + 1] = y[1];
                Y[r * 129 + c4 + 2] = y[2]; Y[r * 129 + c4 + 3] = y[3];
                const float ebi = eb[r];
                #pragma unroll
                for (int e = 0; e < 4; ++e) {
                    const float dlt = ea[c4 + e] - ebi;
                    lap += x[e] * x[e] * dlt * dlt;
                }
            }
        }
        __syncthreads();
        const int i0 = ty * 8, k0 = tx * 8;
        float z[8][8];
        #pragma unroll
        for (int i = 0; i < 8; ++i)
            #pragma unroll
            for (int t = 0; t < 8; ++t) z[i][t] = 0.0f;
        for (int j = 0; j < K; ++j) {
            float xi[8], yk[8];
            if (p < 2) {
                #pragma unroll
                for (int i = 0; i < 8; ++i) xi[i] = X[(i0 + i) * 129 + j];
                #pragma unroll
                for (int t = 0; t < 8; ++t) yk[t] = Y[j * 129 + k0 + t];
            } else {
                #pragma unroll
                for (int i = 0; i < 8; ++i) xi[i] = X[j * 129 + i0 + i];
                #pragma unroll
                for (int t = 0; t < 8; ++t) yk[t] = X[j * 129 + k0 + t];
            }
            #pragma unroll
            for (int i = 0; i < 8; ++i)
                #pragma unroll
                for (int t = 0; t < 8; ++t) z[i][t] += xi[i] * yk[t];
        }
        float s = 0.0f;
        #pragma unroll
        for (int i = 0; i < 8; ++i)
            #pragma unroll
            for (int t = 0; t < 8; ++t) {
                const float e = z[i][t] - ((i0 + i) == (k0 + t) ? 1.0f : 0.0f);
                s += e * e;
            }
        #pragma unroll
        for (int off = 32; off; off >>= 1) {
            s   += __shfl_down(s, off, 64);
            lap += __shfl_down(lap, off, 64);
        }
        if ((tid & 63) == 0) {
            if (p < 2) {
                atomicAdd(out + 0, s * (W_BIJ / (float)N));
                atomicAdd(out + 2, lap * (W_LAP / (float)N));
            } else {
                atomicAdd(out + 1, s * (W_ORTH / (float)N));
            }
        }
    }
}

extern "C" void kernel_launch(void* const* d_in, const int* in_sizes, int n_in,
                              void* d_out, int out_size, void* d_ws, size_t ws_size,
                              hipStream_t stream) {
    (void)n_in;
    const float* C12 = (const float*)d_in[0];
    const float* C21 = (const float*)d_in[1];
    const float* F1  = (const float*)d_in[2];
    const float* F2  = (const float*)d_in[3];
    const float* E1  = (const float*)d_in[4];
    const float* E2  = (const float*)d_in[5];
    const float* T1  = (const float*)d_in[6];
    const float* T2  = (const float*)d_in[7];
    const float* ev1 = (const float*)d_in[8];
    const float* ev2 = (const float*)d_in[9];
    const int* desc  = (const int*)d_in[10];
    float* out = (float*)d_out;

    const int N  = in_sizes[8] / K;            // evals_1: N*K
    const int ND = in_sizes[10];               // desc_ind
    const int V  = in_sizes[4] / (N * K);      // evecs_1: N*V*K
    const int CF = in_sizes[2] / (N * V);      // feat_1: N*V*C

    hipMemsetAsync(d_out, 0, (size_t)out_size * sizeof(float), stream);

    const size_t ABF = (size_t)16 * NCH * TILE_B;        // 20,709,376
    const size_t EBF = ABF;                              // 20,709,376
    const size_t FBF = (size_t)400 * VPAD * 4;           //  8,089,600
    const size_t CBF = (size_t)32 * CTILE_B;             //  1,048,576
    const size_t MBF = (size_t)400 * 65536;              // 26,214,400
    const size_t need = ABF + EBF + FBF + CBF + MBF;     // ~76.8 MB

    const bool okShape = (N == 8 && ND == 25 && V == 5000 && CF == 128);
    if (!okShape || ws_size < need) {
        const size_t shmem = (size_t)(2 * K * 129) * sizeof(float);  // 132096
        hipFuncSetAttribute((const void*)surfm_fused,
                            hipFuncAttributeMaxDynamicSharedMemorySize, (int)shmem);
        const int blocks = N * ND + 4 * N;
        surfm_fused<<<blocks, 256, shmem, stream>>>(C12, C21, F1, F2, E1, E2, T1, T2,
                                                    ev1, ev2, desc, out, N, ND, V, CF);
        return;
    }

    char* ws = (char*)d_ws;
    unsigned short* Abf = (unsigned short*)ws;
    unsigned short* Ebf = (unsigned short*)(ws + ABF);
    float* Fbf = (float*)(ws + ABF + EBF);
    char* Cbf = ws + ABF + EBF + FBF;
    char* Mbf = ws + ABF + EBF + FBF + CBF;

    surfm_conv<<<2944, 256, 0, stream>>>(T1, T2, E1, E2, F1, F2, C12, C21, desc,
                                         Abf, Ebf, Fbf, Cbf, V, CF);

    const size_t shmem1 = 106496;   // A dbuf 32K + E dbuf 32K + w 40960
    hipFuncSetAttribute((const void*)surfm_stage1,
                        hipFuncAttributeMaxDynamicSharedMemorySize, (int)shmem1);
    surfm_stage1<<<208, 512, shmem1, stream>>>((const char*)Abf, (const char*)Ebf,
                                               Fbf, Mbf);

    const size_t shmem2 = 132096;   // max(4x32K tiles, small-loss 2*K*129 fp32)
    hipFuncSetAttribute((const void*)surfm_stage2,
                        hipFuncAttributeMaxDynamicSharedMemorySize, (int)shmem2);
    surfm_stage2<<<N * ND + 4 * N, 256, shmem2, stream>>>(C12, C21, ev1, ev2,
                                                          Cbf, Mbf, out, N, ND);
}

// Round 5
// 187.556 us; speedup vs baseline: 8.1384x; 1.0740x over previous
//
#include <hip/hip_runtime.h>

typedef float v4f __attribute__((ext_vector_type(4)));
typedef unsigned int u32;
typedef __attribute__((ext_vector_type(4))) u32 u32x4;
typedef __attribute__((ext_vector_type(8))) short bhalf8;

#define K 128
#define W_BIJ 1000.0f
#define W_ORTH 1000.0f
#define W_LAP 1.0f
#define W_PRE 100000.0f

#define NCH 79          // ceil(5000/64) V-chunks of 64
#define TILE_B 16384    // 128 rows x 64 k bf16 tile
#define CTILE_B 32768   // 128 x 128 bf16 tile
#define VPAD 5120       // NCH*64 rounded to 2*2560 (S=2 halves of 2560)

union B8 { u32x4 u; bhalf8 h; };

static __device__ __forceinline__ unsigned short f2b(float x) {
    union { float f; unsigned int u; } v; v.f = x;
    unsigned int u = v.u + 0x7FFFu + ((v.u >> 16) & 1u);   // RNE
    return (unsigned short)(u >> 16);
}
static __device__ __forceinline__ u32 pk2(float lo, float hi) {
    return (u32)f2b(lo) | ((u32)f2b(hi) << 16);
}
static __device__ __forceinline__ float bitsf(u32 x) {
    union { u32 u; float f; } v; v.u = x; return v.f;
}
static __device__ __forceinline__ u32 cvtpk(float lo, float hi) {
    u32 r; asm("v_cvt_pk_bf16_f32 %0, %1, %2" : "=v"(r) : "v"(lo), "v"(hi)); return r;
}
static __device__ __forceinline__ void gload_lds16(const void* g, void* l) {
    __builtin_amdgcn_global_load_lds((const __attribute__((address_space(1))) u32*)g,
                                     (__attribute__((address_space(3))) u32*)l, 16, 0, 0);
}

// ============================= conv kernel ==================================
// blocks [0,1264):      Abf tiles  (T1/T2 -> PRE-SWIZZLED 128x64 bf16, gload_lds-ready)
// blocks [1264,2528):   Ebf tiles  (E1/E2 -> transposed [j][v] bf16, UNSWIZZLED: read to regs)
// blocks [2528,2928):   Fbf        (feat column gather -> fp32 [mat][n][d][VPAD])
// blocks [2928,2944):   Cbf        (C12/C21 -> n-layout + t-layout swizzled bf16 tiles)
extern "C" __global__ __launch_bounds__(256, 2)
void surfm_conv(const float* __restrict__ T1, const float* __restrict__ T2,
                const float* __restrict__ E1, const float* __restrict__ E2,
                const float* __restrict__ F1, const float* __restrict__ F2,
                const float* __restrict__ C12g, const float* __restrict__ C21g,
                const int* __restrict__ desc,
                unsigned short* __restrict__ Abf, unsigned short* __restrict__ Ebf,
                float* __restrict__ Fbf, char* __restrict__ Cbf,
                int V, int CF)
{
    __shared__ char csm[32768];
    const int b = blockIdx.x;
    const int tid = threadIdx.x;

    if (b < 1264) {
        // ---------------- Abf: [mn][c] tiles, (r, k) pre-swizzled ------------
        const int c  = b % NCH;
        const int mn = b / NCH;
        const float* src = ((mn & 8) ? T2 : T1) + (size_t)(mn & 7) * K * V;
        char* dst = (char*)Abf + (size_t)b * TILE_B;
        #pragma unroll
        for (int it = 0; it < 4; ++it) {
            const int item = it * 256 + tid;         // 1024 = 128 r x 8 grp
            const int grp = item & 7, r = item >> 3;
            const int kg = grp ^ (r & 7);
            const int k = c * 64 + kg * 8;
            u32x4 o = (u32x4){0u,0u,0u,0u};
            if (k + 8 <= V) {
                const v4f lo = *(const v4f*)(src + (size_t)r * V + k);
                const v4f hi = *(const v4f*)(src + (size_t)r * V + k + 4);
                o[0] = pk2(lo[0], lo[1]); o[1] = pk2(lo[2], lo[3]);
                o[2] = pk2(hi[0], hi[1]); o[3] = pk2(hi[2], hi[3]);
            }
            *(u32x4*)(dst + r * 128 + grp * 16) = o;
        }
    } else if (b < 2528) {
        // ---------------- Ebf: transposed [j=128][v=64] bf16, unswizzled -----
        const int idx = b - 1264;
        const int c  = idx % NCH;
        const int mn = idx / NCH;
        const float* src = ((mn & 8) ? E2 : E1) + (size_t)(mn & 7) * V * K;
        char* dst = (char*)Ebf + (size_t)idx * TILE_B;
        #pragma unroll
        for (int it = 0; it < 8; ++it) {
            const int item = it * 256 + tid;          // 2048 = 32 vp x 32 j4
            const int vp = item >> 5;                 // v-pair 0..31
            const int j4 = (item & 31) * 4;
            const int v = c * 64 + vp * 2;
            v4f e0 = {0.f,0.f,0.f,0.f}, e1 = e0;
            if (v < V)     e0 = *(const v4f*)(src + (size_t)v * K + j4);
            if (v + 1 < V) e1 = *(const v4f*)(src + (size_t)(v + 1) * K + j4);
            #pragma unroll
            for (int e = 0; e < 4; ++e) {
                const int j = j4 + e;
                *(u32*)(csm + j * 128 + vp * 4) = pk2(e0[e], e1[e]);
            }
        }
        __syncthreads();
        #pragma unroll
        for (int it = 0; it < 4; ++it) {
            const int item = it * 256 + tid;
            *(u32x4*)(dst + item * 16) = *(const u32x4*)(csm + item * 16);
        }
    } else if (b < 2928) {
        // ---------------- Fbf: w[v] = feat[n][v][desc[d]] fp32, padded -------
        const int idx = b - 2528;                     // mn*25 + d
        const int d  = idx % 25;
        const int mn = idx / 25;
        const int col = desc[d];
        const float* src = ((mn & 8) ? F2 : F1) + (size_t)(mn & 7) * V * CF + col;
        float* dst = Fbf + (size_t)idx * VPAD;
        for (int i = tid; i < VPAD; i += 256)
            dst[i] = (i < V) ? src[(size_t)i * CF] : 0.0f;
    } else {
        // ---------------- Cbf: n-layout + t-layout 128x128 bf16 tiles --------
        const int idx = b - 2928;                     // mat*8 + n
        const float* src = ((idx & 8) ? C21g : C12g) + (size_t)(idx & 7) * K * K;
        char* outN = Cbf + (size_t)(idx * 2 + 0) * CTILE_B;
        char* outT = Cbf + (size_t)(idx * 2 + 1) * CTILE_B;
        #pragma unroll
        for (int it = 0; it < 8; ++it) {
            const int item = it * 256 + tid;          // 2048 = 128 r x 16 grp
            const int r = item >> 4, grp = item & 15;
            const int g = grp ^ (r & 7);
            const v4f lo = *(const v4f*)(src + r * K + g * 8);
            const v4f hi = *(const v4f*)(src + r * K + g * 8 + 4);
            u32x4 o;
            o[0] = pk2(lo[0], lo[1]); o[1] = pk2(lo[2], lo[3]);
            o[2] = pk2(hi[0], hi[1]); o[3] = pk2(hi[2], hi[3]);
            *(u32x4*)(outN + r * 256 + grp * 16) = o;
        }
        #pragma unroll
        for (int it = 0; it < 8; ++it) {
            const int item = it * 256 + tid;          // 2048 = 64 rp x 32 j4
            const int rp = item >> 5;
            const int j4 = (item & 31) * 4;
            const v4f r0 = *(const v4f*)(src + (2 * rp) * K + j4);
            const v4f r1 = *(const v4f*)(src + (2 * rp + 1) * K + j4);
            #pragma unroll
            for (int e = 0; e < 4; ++e) {
                const int j = j4 + e;
                *(u32*)(csm + j * 256 + ((rp * 4) ^ ((j & 7) << 4))) = pk2(r0[e], r1[e]);
            }
        }
        __syncthreads();
        #pragma unroll
        for (int it = 0; it < 8; ++it) {
            const int item = it * 256 + tid;
            *(u32x4*)(outT + item * 16) = *(const u32x4*)(csm + item * 16);
        }
    }
}

// ============================= stage 1 ======================================
// 416 blocks x 512 threads: b -> n=b&7 (XCD), vh=(b>>3)&1 (V-half), mat, dgi.
// Wave-tile 128x16 (mf=8, jf=1): E-frags PRIVATE per wave -> registers.
// LDS = A dbuf 32K + w 20K = 52K -> 2 blocks/CU. fp32 M^T partials out.
extern "C" __global__ __launch_bounds__(512, 4)
void surfm_stage1(const char* __restrict__ Abf, const char* __restrict__ Ebf,
                  const float* __restrict__ Fbf, float* __restrict__ Mpart,
                  int partStride)
{
    extern __shared__ char sm[];     // [0,32768) A dbuf; [32768, 53248) w fp32
    const int tid = threadIdx.x;
    const int l  = tid & 63;
    const int wv = tid >> 6;
    const int wq = __builtin_amdgcn_readfirstlane(wv);
    const int b = blockIdx.x;
    const int n = b & 7;
    const int vh = (b >> 3) & 1;
    const int rest = b >> 4;            // 0..25
    const int mat = rest & 1;
    const int dgi = rest >> 1;          // 0..12
    const int d0 = dgi * 2;
    const bool hasD1 = (d0 + 1) < 25;

    const int mn = mat * 8 + n;
    const char* gA = Abf + (size_t)mn * NCH * TILE_B;
    const char* gE = Ebf + (size_t)mn * NCH * TILE_B;
    const char* gW = (const char*)(Fbf + ((size_t)mn * 25 + d0) * VPAD) + vh * 10240;

    const int c0 = vh ? 40 : 0;
    const int NT = vh ? 39 : 40;

    const int lm = l & 15;
    const int lk = (l >> 4) * 8;
    const int j  = wq * 16 + lm;            // this wave's private E column
    const int rkey = (lm & 7) << 4;         // A swizzle key: (r&7) == (lm&7)
    float* wLds = (float*)(sm + 32768);

    v4f acc0[8], acc1[8];
    #pragma unroll
    for (int mf = 0; mf < 8; ++mf) {
        acc0[mf] = (v4f){0.f,0.f,0.f,0.f};
        acc1[mf] = (v4f){0.f,0.f,0.f,0.f};
    }

    // prologue: w (2 d x 10KB) + A chunk c0 + E chunk c0 regs
    for (int i = wq; i < 20; i += 8) {
        const int dd = i / 10, off = (i - dd * 10) * 1024;
        gload_lds16(gW + dd * 20480 + off + l * 16, sm + 32768 + dd * 10240 + off);
    }
    {
        const char* t = gA + (size_t)c0 * TILE_B;
        gload_lds16(t + (wq * 2 + 0) * 1024 + l * 16, sm + (wq * 2 + 0) * 1024);
        gload_lds16(t + (wq * 2 + 1) * 1024 + l * 16, sm + (wq * 2 + 1) * 1024);
    }
    const char* gEl = gE + j * 128 + lk * 2;
    u32x4 eC0 = *(const u32x4*)(gEl + (size_t)c0 * TILE_B);
    u32x4 eC1 = *(const u32x4*)(gEl + (size_t)c0 * TILE_B + 64);
    asm volatile("s_waitcnt vmcnt(0)" ::: "memory");
    __builtin_amdgcn_s_barrier();

    #pragma unroll 1
    for (int t = 0; t < NT; ++t) {
        const int par = t & 1;
        u32x4 eN0 = eC0, eN1 = eC1;
        if (t + 1 < NT) {
            const char* tA = gA + (size_t)(c0 + t + 1) * TILE_B;
            char* dA = sm + (par ^ 1) * 16384;
            gload_lds16(tA + (wq * 2 + 0) * 1024 + l * 16, dA + (wq * 2 + 0) * 1024);
            gload_lds16(tA + (wq * 2 + 1) * 1024 + l * 16, dA + (wq * 2 + 1) * 1024);
            const char* tE = gEl + (size_t)(c0 + t + 1) * TILE_B;
            eN0 = *(const u32x4*)(tE);
            eN1 = *(const u32x4*)(tE + 64);
            asm volatile("s_waitcnt vmcnt(4)" ::: "memory");   // keep c+1's 4 in flight
        } else {
            asm volatile("s_waitcnt vmcnt(0)" ::: "memory");
        }
        __builtin_amdgcn_s_barrier();
        __builtin_amdgcn_sched_barrier(0);

        const char* Ab = sm + par * 16384;
        #pragma unroll
        for (int ks = 0; ks < 2; ++ks) {
            const u32x4 e = ks ? eC1 : eC0;
            const float* pw0 = wLds + t * 64 + ks * 32 + lk;
            const float* pw1 = pw0 + 2560;
            const v4f w0a = *(const v4f*)pw0, w0b = *(const v4f*)(pw0 + 4);
            const v4f w1a = *(const v4f*)pw1, w1b = *(const v4f*)(pw1 + 4);
            const float wl0[4] = {w0a[0], w0a[2], w0b[0], w0b[2]};
            const float wh0[4] = {w0a[1], w0a[3], w0b[1], w0b[3]};
            const float wl1[4] = {w1a[0], w1a[2], w1b[0], w1b[2]};
            const float wh1[4] = {w1a[1], w1a[3], w1b[1], w1b[3]};
            B8 p0, p1;
            #pragma unroll
            for (int t4 = 0; t4 < 4; ++t4) {
                const float elo = bitsf(e[t4] << 16);
                const float ehi = bitsf(e[t4] & 0xFFFF0000u);
                p0.u[t4] = cvtpk(elo * wl0[t4], ehi * wh0[t4]);
                p1.u[t4] = cvtpk(elo * wl1[t4], ehi * wh1[t4]);
            }
            const int kb = ks * 64 + lk * 2;
            #pragma unroll
            for (int mf = 0; mf < 8; ++mf) {
                const int r = mf * 16 + lm;
                B8 a; a.u = *(const u32x4*)(Ab + r * 128 + (kb ^ rkey));
                acc0[mf] = __builtin_amdgcn_mfma_f32_16x16x32_bf16(a.h, p0.h, acc0[mf], 0, 0, 0);
                acc1[mf] = __builtin_amdgcn_mfma_f32_16x16x32_bf16(a.h, p1.h, acc1[mf], 0, 0, 0);
            }
        }
        eC0 = eN0; eC1 = eN1;
        __builtin_amdgcn_s_barrier();
    }

    // epilogue: fp32 M^T partial stores [col j][row], v4f coalesced
    const int slotM = (n * 25 + d0) * 2 + mat;
    const int rbase = (l >> 4) * 4;
    {
        float* dst = Mpart + ((size_t)(vh * partStride + slotM)) * 16384 + j * 128 + rbase;
        if (partStride) {
            #pragma unroll
            for (int mf = 0; mf < 8; ++mf) *(v4f*)(dst + mf * 16) = acc0[mf];
        } else {
            #pragma unroll
            for (int mf = 0; mf < 8; ++mf)
                #pragma unroll
                for (int e = 0; e < 4; ++e) atomicAdd(dst + mf * 16 + e, acc0[mf][e]);
        }
    }
    if (hasD1) {
        float* dst = Mpart + ((size_t)(vh * partStride + slotM + 2)) * 16384 + j * 128 + rbase;
        if (partStride) {
            #pragma unroll
            for (int mf = 0; mf < 8; ++mf) *(v4f*)(dst + mf * 16) = acc1[mf];
        } else {
            #pragma unroll
            for (int mf = 0; mf < 8; ++mf)
                #pragma unroll
                for (int e = 0; e < 4; ++e) atomicAdd(dst + mf * 16 + e, acc1[mf][e]);
        }
    }
}

// ============================= mconv ========================================
// 400 blocks: sum nPart fp32 M^T partials -> n-layout + t-layout bf16 tiles.
extern "C" __global__ __launch_bounds__(256, 2)
void surfm_mconv(const float* __restrict__ Mpart, int nPart,
                 char* __restrict__ Mbf)
{
    extern __shared__ char sm[];
    float* sMT = (float*)sm;                  // [128 j][132]
    const int s = blockIdx.x;
    const int tid = threadIdx.x;
    const float* p0 = Mpart + (size_t)s * 16384;
    for (int i = tid; i < 4096; i += 256) {
        const int jj = i >> 5, r4 = (i & 31) * 4;
        v4f v = *(const v4f*)(p0 + jj * 128 + r4);
        if (nPart == 2) v += *(const v4f*)(p0 + (size_t)400 * 16384 + jj * 128 + r4);
        *(v4f*)(sMT + jj * 132 + r4) = v;
    }
    __syncthreads();
    char* outN = Mbf + (size_t)s * 65536;
    char* outT = outN + 32768;
    #pragma unroll
    for (int it = 0; it < 16; ++it) {
        const int item = it * 256 + tid;       // 4096 = 2 lay x (128 r x 16 grp)
        const int lay = item >> 11;
        const int g2 = item & 2047;
        const int rr = g2 >> 4, grp = g2 & 15;
        const int g = grp ^ (rr & 7);
        u32x4 o;
        if (lay == 0) {                        // t-layout: M^T row rr contiguous
            const float* p = sMT + rr * 132 + g * 8;
            const v4f a = *(const v4f*)p, bq = *(const v4f*)(p + 4);
            o[0] = pk2(a[0], a[1]);   o[1] = pk2(a[2], a[3]);
            o[2] = pk2(bq[0], bq[1]); o[3] = pk2(bq[2], bq[3]);
            *(u32x4*)(outT + rr * 256 + grp * 16) = o;
        } else {                               // n-layout: M row rr = sMT column
            const float* p = sMT + (g * 8) * 132 + rr;
            o[0] = pk2(p[0],   p[132]); o[1] = pk2(p[264], p[396]);
            o[2] = pk2(p[528], p[660]); o[3] = pk2(p[792], p[924]);
            *(u32x4*)(outN + rr * 256 + grp * 16) = o;
        }
    }
}

// ============================= stage 2 ======================================
// blocks [0,200): l_pre residual GEMMs via MFMA from pre-built bf16 tiles.
// blocks [200,232): small losses (bij/orth/lap), verified fp32 path.
extern "C" __global__ __launch_bounds__(256, 1)
void surfm_stage2(const float* __restrict__ C12g, const float* __restrict__ C21g,
                  const float* __restrict__ ev1g, const float* __restrict__ ev2g,
                  const char* __restrict__ Cbf, const char* __restrict__ Mbf,
                  float* __restrict__ out, int N, int ND)
{
    extern __shared__ char sm[];
    const int b = blockIdx.x;
    const int tid = threadIdx.x;
    const int nPre = N * ND;

    if (b < nPre) {
        const int n = b & 7, d = b >> 3;
        const size_t slot = n * 25 + d;
        const int l = tid & 63;
        const int wq = __builtin_amdgcn_readfirstlane(tid >> 6);
        const int lm = l & 15, lk = (l >> 4) * 8;
        const int wm = wq >> 1, wj = wq & 1;
        float rsum = 0.0f;

        #pragma unroll 1
        for (int ph = 0; ph < 2; ++ph) {
            const char* s0 = Cbf + ((size_t)(ph * 8 + n) * 2 + 0) * CTILE_B;
            const char* s1 = Mbf + (slot * 2 + (ph ? 1 : 0)) * 65536 + 32768;
            const char* s2 = Mbf + (slot * 2 + (ph ? 0 : 1)) * 65536;
            const char* s3 = Cbf + ((size_t)(ph * 8 + n) * 2 + 1) * CTILE_B;
            const char* gs = (wq == 0) ? s0 : (wq == 1) ? s1 : (wq == 2) ? s2 : s3;
            char* ld = sm + wq * 32768;
            if (ph) __builtin_amdgcn_s_barrier();
            #pragma unroll
            for (int i = 0; i < 32; ++i)
                gload_lds16(gs + i * 1024 + l * 16, ld + i * 1024);
            asm volatile("s_waitcnt vmcnt(0)" ::: "memory");
            __builtin_amdgcn_s_barrier();
            __builtin_amdgcn_sched_barrier(0);

            v4f as_[4][4], at_[4][4];
            #pragma unroll
            for (int mf = 0; mf < 4; ++mf)
                #pragma unroll
                for (int jf = 0; jf < 4; ++jf) {
                    as_[mf][jf] = (v4f){0.f,0.f,0.f,0.f};
                    at_[mf][jf] = (v4f){0.f,0.f,0.f,0.f};
                }
            #pragma unroll
            for (int ks = 0; ks < 4; ++ks) {
                const int kb = ks * 64 + lk * 2;
                B8 bS[4], bT[4];
                #pragma unroll
                for (int jf = 0; jf < 4; ++jf) {
                    const int jj = wj * 64 + jf * 16 + lm;
                    const int off = jj * 256 + (kb ^ ((jj & 7) << 4));
                    bS[jf].u = *(const u32x4*)(sm + 32768 + off);
                    bT[jf].u = *(const u32x4*)(sm + 98304 + off);
                }
                #pragma unroll
                for (int mf = 0; mf < 4; ++mf) {
                    const int r = wm * 64 + mf * 16 + lm;
                    const int off = r * 256 + (kb ^ ((r & 7) << 4));
                    B8 aS; aS.u = *(const u32x4*)(sm + off);
                    B8 aT; aT.u = *(const u32x4*)(sm + 65536 + off);
                    #pragma unroll
                    for (int jf = 0; jf < 4; ++jf) {
                        as_[mf][jf] = __builtin_amdgcn_mfma_f32_16x16x32_bf16(aS.h, bS[jf].h, as_[mf][jf], 0, 0, 0);
                        at_[mf][jf] = __builtin_amdgcn_mfma_f32_16x16x32_bf16(aT.h, bT[jf].h, at_[mf][jf], 0, 0, 0);
                    }
                }
            }
            #pragma unroll
            for (int mf = 0; mf < 4; ++mf)
                #pragma unroll
                for (int jf = 0; jf < 4; ++jf) {
                    const v4f df = as_[mf][jf] - at_[mf][jf];
                    rsum += df[0]*df[0] + df[1]*df[1] + df[2]*df[2] + df[3]*df[3];
                }
        }
        #pragma unroll
        for (int off = 32; off; off >>= 1) rsum += __shfl_down(rsum, off, 64);
        if (l == 0)
            atomicAdd(out + 3, rsum * (W_PRE / (float)(N * K * K)));
    } else {
        // --------------------------- small losses ---------------------------
        float* lds = (float*)sm;
        const int idx = b - nPre;
        const int n = idx >> 2, p = idx & 3;
        const float* c12 = C12g + (size_t)n * K * K;
        const float* c21 = C21g + (size_t)n * K * K;
        const float* Xg = (p == 1 || p == 3) ? c21 : c12;
        const float* Yg = (p == 0) ? c21 : c12;
        const float* ea = (p == 0) ? ev1g + n * K : ev2g + n * K;
        const float* eb = (p == 0) ? ev2g + n * K : ev1g + n * K;
        float* X = lds;             // [K][129]
        float* Y = lds + K * 129;
        const int tx = tid & 15, ty = tid >> 4;
        float lap = 0.0f;
        for (int i = tid; i < K * K / 4; i += 256) {
            const int r = i >> 5, c4 = (i & 31) * 4;
            const v4f x = *(const v4f*)(Xg + r * K + c4);
            X[r * 129 + c4 + 0] = x[0]; X[r * 129 + c4 + 1] = x[1];
            X[r * 129 + c4 + 2] = x[2]; X[r * 129 + c4 + 3] = x[3];
            if (p < 2) {
                const v4f y = *(const v4f*)(Yg + r * K + c4);
                Y[r * 129 + c4 + 0] = y[0]; Y[r * 129 + c4 + 1] = y[1];
                Y[r * 129 + c4 + 2] = y[2]; Y[r * 129 + c4 + 3] = y[3];
                const float ebi = eb[r];
                #pragma unroll
                for (int e = 0; e < 4; ++e) {
                    const float dlt = ea[c4 + e] - ebi;
                    lap += x[e] * x[e] * dlt * dlt;
                }
            }
        }
        __syncthreads();
        const int i0 = ty * 8, k0 = tx * 8;
        float z[8][8];
        #pragma unroll
        for (int i = 0; i < 8; ++i)
            #pragma unroll
            for (int t = 0; t < 8; ++t) z[i][t] = 0.0f;
        for (int jj = 0; jj < K; ++jj) {
            float xi[8], yk[8];
            if (p < 2) {
                #pragma unroll
                for (int i = 0; i < 8; ++i) xi[i] = X[(i0 + i) * 129 + jj];
                #pragma unroll
                for (int t = 0; t < 8; ++t) yk[t] = Y[jj * 129 + k0 + t];
            } else {
                #pragma unroll
                for (int i = 0; i < 8; ++i) xi[i] = X[jj * 129 + i0 + i];
                #pragma unroll
                for (int t = 0; t < 8; ++t) yk[t] = X[jj * 129 + k0 + t];
            }
            #pragma unroll
            for (int i = 0; i < 8; ++i)
                #pragma unroll
                for (int t = 0; t < 8; ++t) z[i][t] += xi[i] * yk[t];
        }
        float sacc = 0.0f;
        #pragma unroll
        for (int i = 0; i < 8; ++i)
            #pragma unroll
            for (int t = 0; t < 8; ++t) {
                const float e = z[i][t] - ((i0 + i) == (k0 + t) ? 1.0f : 0.0f);
                sacc += e * e;
            }
        #pragma unroll
        for (int off = 32; off; off >>= 1) {
            sacc += __shfl_down(sacc, off, 64);
            lap  += __shfl_down(lap, off, 64);
        }
        if ((tid & 63) == 0) {
            if (p < 2) {
                atomicAdd(out + 0, sacc * (W_BIJ / (float)N));
                atomicAdd(out + 2, lap * (W_LAP / (float)N));
            } else {
                atomicAdd(out + 1, sacc * (W_ORTH / (float)N));
            }
        }
    }
}

// ================= fallback: round-2 verified fused kernel =================
extern "C" __global__ __launch_bounds__(256, 1)
void surfm_fused(const float* __restrict__ C12g, const float* __restrict__ C21g,
                 const float* __restrict__ F1, const float* __restrict__ F2,
                 const float* __restrict__ E1g, const float* __restrict__ E2g,
                 const float* __restrict__ T1, const float* __restrict__ T2,
                 const float* __restrict__ ev1g, const float* __restrict__ ev2g,
                 const int* __restrict__ desc, float* __restrict__ out,
                 int N, int ND, int V, int CF)
{
    extern __shared__ char smem[];
    const int b   = blockIdx.x;
    const int tid = threadIdx.x;
    const int nPre = N * ND;

    if (b < nPre) {
        const int n = b & 7;
        const int d = b >> 3;
        const int col = desc[d];
        const float* A1g = T1 + (size_t)n * K * V;
        const float* A2g = T2 + (size_t)n * K * V;
        const float* B1g = E1g + (size_t)n * V * K;
        const float* B2g = E2g + (size_t)n * V * K;
        const float* w1g = F1 + (size_t)n * V * CF;
        const float* w2g = F2 + (size_t)n * V * CF;

        char* As1 = smem;
        char* As2 = smem + 32768;
        char* Bt1 = smem + 65536;
        char* Bt2 = smem + 98304;

        const int l  = tid & 63;
        const int w  = tid >> 6;
        const int lm = l & 15;
        const int lk = (l >> 4) * 8;

        v4f acc1[8][2], acc2[8][2];
        #pragma unroll
        for (int mf = 0; mf < 8; ++mf)
            #pragma unroll
            for (int jf = 0; jf < 2; ++jf) {
                acc1[mf][jf] = (v4f){0.f,0.f,0.f,0.f};
                acc2[mf][jf] = (v4f){0.f,0.f,0.f,0.f};
            }

        for (int v0 = 0; v0 < V; v0 += 128) {
            __syncthreads();
            #pragma unroll 4
            for (int it = 0; it < 16; ++it) {
                const int i  = it * 256 + tid;
                const int r  = i >> 5;
                const int c4 = (i & 31) * 4;
                const int vg = v0 + c4;
                v4f a1 = {0.f,0.f,0.f,0.f}, a2 = {0.f,0.f,0.f,0.f};
                if (vg < V) {
                    a1 = *(const v4f*)(A1g + (size_t)r * V + vg);
                    a2 = *(const v4f*)(A2g + (size_t)r * V + vg);
                }
                const int byte = (r * 256 + c4 * 2) ^ ((r & 7) << 4);
                short4 p1, p2;
                p1.x = (short)f2b(a1[0]); p1.y = (short)f2b(a1[1]);
                p1.z = (short)f2b(a1[2]); p1.w = (short)f2b(a1[3]);
                p2.x = (short)f2b(a2[0]); p2.y = (short)f2b(a2[1]);
                p2.z = (short)f2b(a2[2]); p2.w = (short)f2b(a2[3]);
                *(short4*)(As1 + byte) = p1;
                *(short4*)(As2 + byte) = p2;
            }
            #pragma unroll 2
            for (int it = 0; it < 8; ++it) {
                const int i  = it * 256 + tid;
                const int j4 = (i & 31) * 4;
                const int vp = (i >> 5) * 2;
                const int va = v0 + vp, vb = va + 1;
                v4f e1a = {0.f,0.f,0.f,0.f}, e1b = e1a, e2a = e1a, e2b = e1a;
                if (va < V) {
                    const float w1 = w1g[(size_t)va * CF + col];
                    const float w2 = w2g[(size_t)va * CF + col];
                    e1a = *(const v4f*)(B1g + (size_t)va * K + j4) * w1;
                    e2a = *(const v4f*)(B2g + (size_t)va * K + j4) * w2;
                }
                if (vb < V) {
                    const float w1 = w1g[(size_t)vb * CF + col];
                    const float w2 = w2g[(size_t)vb * CF + col];
                    e1b = *(const v4f*)(B1g + (size_t)vb * K + j4) * w1;
                    e2b = *(const v4f*)(B2g + (size_t)vb * K + j4) * w2;
                }
                #pragma unroll
                for (int e = 0; e < 4; ++e) {
                    const int j = j4 + e;
                    const int key = (((j & 7) ^ ((j >> 3) & 7)) << 4);
                    const int byte = (j * 256 + vp * 2) ^ key;
                    *(u32*)(Bt1 + byte) = pk2(e1a[e], e1b[e]);
                    *(u32*)(Bt2 + byte) = pk2(e2a[e], e2b[e]);
                }
            }
            __syncthreads();
            #pragma unroll
            for (int ks = 0; ks < 4; ++ks) {
                const int k0 = ks * 32 + lk;
                bhalf8 bB1[2], bB2[2];
                #pragma unroll
                for (int jf = 0; jf < 2; ++jf) {
                    const int j = w * 32 + jf * 16 + lm;
                    const int key = (((j & 7) ^ ((j >> 3) & 7)) << 4);
                    const int byte = (j * 256 + k0 * 2) ^ key;
                    bB1[jf] = *(const bhalf8*)(Bt1 + byte);
                    bB2[jf] = *(const bhalf8*)(Bt2 + byte);
                }
                #pragma unroll
                for (int mf = 0; mf < 8; ++mf) {
                    const int r = mf * 16 + lm;
                    const int byte = (r * 256 + k0 * 2) ^ ((r & 7) << 4);
                    const bhalf8 a1 = *(const bhalf8*)(As1 + byte);
                    const bhalf8 a2 = *(const bhalf8*)(As2 + byte);
                    acc1[mf][0] = __builtin_amdgcn_mfma_f32_16x16x32_bf16(a1, bB1[0], acc1[mf][0], 0, 0, 0);
                    acc1[mf][1] = __builtin_amdgcn_mfma_f32_16x16x32_bf16(a1, bB1[1], acc1[mf][1], 0, 0, 0);
                    acc2[mf][0] = __builtin_amdgcn_mfma_f32_16x16x32_bf16(a2, bB2[0], acc2[mf][0], 0, 0, 0);
                    acc2[mf][1] = __builtin_amdgcn_mfma_f32_16x16x32_bf16(a2, bB2[1], acc2[mf][1], 0, 0, 0);
                }
            }
        }
        __syncthreads();
        float* M1 = (float*)smem;
        float* M2 = (float*)smem + K * K;
        #pragma unroll
        for (int mf = 0; mf < 8; ++mf)
            #pragma unroll
            for (int jf = 0; jf < 2; ++jf)
                #pragma unroll
                for (int rg = 0; rg < 4; ++rg) {
                    const int row = mf * 16 + ((l >> 4) << 2) + rg;
                    const int cj  = w * 32 + jf * 16 + lm;
                    const int pc  = ((((cj >> 2) ^ ((row >> 3) & 7)) << 2) | (cj & 3));
                    M1[row * K + pc] = acc1[mf][jf][rg];
                    M2[row * K + pc] = acc2[mf][jf][rg];
                }
        __syncthreads();

        const int tx = tid & 15, ty = tid >> 4;
        const int r0 = ty * 8;
        const int ca = tx * 4, cb = 64 + tx * 4;
        const int kcol = ty & 7;
        const float* c12 = C12g + (size_t)n * K * K;
        const float* c21 = C21g + (size_t)n * K * K;
        v4f acc1a[8], acc1b[8], acc2a[8], acc2b[8];
        #pragma unroll
        for (int i = 0; i < 8; ++i) {
            acc1a[i] = (v4f){0,0,0,0}; acc1b[i] = (v4f){0,0,0,0};
            acc2a[i] = (v4f){0,0,0,0}; acc2b[i] = (v4f){0,0,0,0};
        }
        for (int jj = 0; jj < K; ++jj) {
            const int keyj = (jj >> 3) & 7;
            const int ga = (tx ^ keyj) << 2;
            const int gb = ((16 + tx) ^ keyj) << 2;
            const v4f m1ra = *(const v4f*)(M1 + jj * K + ga);
            const v4f m1rb = *(const v4f*)(M1 + jj * K + gb);
            const v4f m2ra = *(const v4f*)(M2 + jj * K + ga);
            const v4f m2rb = *(const v4f*)(M2 + jj * K + gb);
            const v4f c12ra = *(const v4f*)(c12 + jj * K + ca);
            const v4f c12rb = *(const v4f*)(c12 + jj * K + cb);
            const v4f c21ra = *(const v4f*)(c21 + jj * K + ca);
            const v4f c21rb = *(const v4f*)(c21 + jj * K + cb);
            const int jp = (((jj >> 2) ^ kcol) << 2) | (jj & 3);
            #pragma unroll
            for (int i = 0; i < 8; ++i) {
                const int r = r0 + i;
                const float x12 = c12[r * K + jj];
                const float x21 = c21[r * K + jj];
                const float m1c = M1[r * K + jp];
                const float m2c = M2[r * K + jp];
                acc1a[i] += m1ra * x12; acc1a[i] -= c12ra * m2c;
                acc1b[i] += m1rb * x12; acc1b[i] -= c12rb * m2c;
                acc2a[i] += m2ra * x21; acc2a[i] -= c21ra * m1c;
                acc2b[i] += m2rb * x21; acc2b[i] -= c21rb * m1c;
            }
        }
        float s = 0.0f;
        #pragma unroll
        for (int i = 0; i < 8; ++i)
            #pragma unroll
            for (int e = 0; e < 4; ++e) {
                s += acc1a[i][e] * acc1a[i][e] + acc1b[i][e] * acc1b[i][e];
                s += acc2a[i][e] * acc2a[i][e] + acc2b[i][e] * acc2b[i][e];
            }
        #pragma unroll
        for (int off = 32; off; off >>= 1) s += __shfl_down(s, off, 64);
        if ((tid & 63) == 0)
            atomicAdd(out + 3, s * (W_PRE / (float)(N * K * K)));
    } else {
        float* ldsf = (float*)smem;
        const int idx = b - nPre;
        const int n = idx >> 2, p = idx & 3;
        const float* c12 = C12g + (size_t)n * K * K;
        const float* c21 = C21g + (size_t)n * K * K;
        const float* Xg = (p == 1 || p == 3) ? c21 : c12;
        const float* Yg = (p == 0) ? c21 : c12;
        const float* ea = (p == 0) ? ev1g + n * K : ev2g + n * K;
        const float* eb = (p == 0) ? ev2g + n * K : ev1g + n * K;
        float* X = ldsf;
        float* Y = ldsf + K * 129;
        const int tx = tid & 15, ty = tid >> 4;
        float lap = 0.0f;
        for (int i = tid; i < K * K / 4; i += 256) {
            const int r = i >> 5, c4 = (i & 31) * 4;
            const v4f x = *(const v4f*)(Xg + r * K + c4);
            X[r * 129 + c4 + 0] = x[0]; X[r * 129 + c4 + 1] = x[1];
            X[r * 129 + c4 + 2] = x[2]; X[r * 129 + c4 + 3] = x[3];
            if (p < 2) {
                const v4f y = *(const v4f*)(Yg + r * K + c4);
                Y[r * 129 + c4 + 0] = y[0]; Y[r * 129 + c4 + 1] = y[1];
                Y[r * 129 + c4 + 2] = y[2]; Y[r * 129 + c4 + 3] = y[3];
                const float ebi = eb[r];
                #pragma unroll
                for (int e = 0; e < 4; ++e) {
                    const float dlt = ea[c4 + e] - ebi;
                    lap += x[e] * x[e] * dlt * dlt;
                }
            }
        }
        __syncthreads();
        const int i0 = ty * 8, k0 = tx * 8;
        float z[8][8];
        #pragma unroll
        for (int i = 0; i < 8; ++i)
            #pragma unroll
            for (int t = 0; t < 8; ++t) z[i][t] = 0.0f;
        for (int jj = 0; jj < K; ++jj) {
            float xi[8], yk[8];
            if (p < 2) {
                #pragma unroll
                for (int i = 0; i < 8; ++i) xi[i] = X[(i0 + i) * 129 + jj];
                #pragma unroll
                for (int t = 0; t < 8; ++t) yk[t] = Y[jj * 129 + k0 + t];
            } else {
                #pragma unroll
                for (int i = 0; i < 8; ++i) xi[i] = X[jj * 129 + i0 + i];
                #pragma unroll
                for (int t = 0; t < 8; ++t) yk[t] = X[jj * 129 + k0 + t];
            }
            #pragma unroll
            for (int i = 0; i < 8; ++i)
                #pragma unroll
                for (int t = 0; t < 8; ++t) z[i][t] += xi[i] * yk[t];
        }
        float s = 0.0f;
        #pragma unroll
        for (int i = 0; i < 8; ++i)
            #pragma unroll
            for (int t = 0; t < 8; ++t) {
                const float e = z[i][t] - ((i0 + i) == (k0 + t) ? 1.0f : 0.0f);
                s += e * e;
            }
        #pragma unroll
        for (int off = 32; off; off >>= 1) {
            s   += __shfl_down(s, off, 64);
            lap += __shfl_down(lap, off, 64);
        }
        if ((tid & 63) == 0) {
            if (p < 2) {
                atomicAdd(out + 0, s * (W_BIJ / (float)N));
                atomicAdd(out + 2, lap * (W_LAP / (float)N));
            } else {
                atomicAdd(out + 1, s * (W_ORTH / (float)N));
            }
        }
    }
}

extern "C" void kernel_launch(void* const* d_in, const int* in_sizes, int n_in,
                              void* d_out, int out_size, void* d_ws, size_t ws_size,
                              hipStream_t stream) {
    (void)n_in;
    const float* C12 = (const float*)d_in[0];
    const float* C21 = (const float*)d_in[1];
    const float* F1  = (const float*)d_in[2];
    const float* F2  = (const float*)d_in[3];
    const float* E1  = (const float*)d_in[4];
    const float* E2  = (const float*)d_in[5];
    const float* T1  = (const float*)d_in[6];
    const float* T2  = (const float*)d_in[7];
    const float* ev1 = (const float*)d_in[8];
    const float* ev2 = (const float*)d_in[9];
    const int* desc  = (const int*)d_in[10];
    float* out = (float*)d_out;

    const int N  = in_sizes[8] / K;            // evals_1: N*K
    const int ND = in_sizes[10];               // desc_ind
    const int V  = in_sizes[4] / (N * K);      // evecs_1: N*V*K
    const int CF = in_sizes[2] / (N * V);      // feat_1: N*V*C

    hipMemsetAsync(d_out, 0, (size_t)out_size * sizeof(float), stream);

    const size_t ABF = (size_t)16 * NCH * TILE_B;        // 20,709,376
    const size_t EBF = ABF;                              // 20,709,376
    const size_t FBF = (size_t)400 * VPAD * 4;           //  8,192,000
    const size_t CBF = (size_t)32 * CTILE_B;             //  1,048,576
    const size_t MBF = (size_t)400 * 65536;              // 26,214,400
    const size_t MP1 = (size_t)400 * 65536;              // one partial set
    const size_t base = ABF + EBF + FBF + CBF + MBF;
    const size_t needPart   = base + 2 * MP1;            // ~129.3 MB
    const size_t needAtomic = base + 1 * MP1;            // ~103.1 MB

    const bool okShape = (N == 8 && ND == 25 && V == 5000 && CF == 128);
    int mode = 0;
    if (okShape && ws_size >= needPart) mode = 2;
    else if (okShape && ws_size >= needAtomic) mode = 1;

    if (mode == 0) {
        const size_t shmem = (size_t)(2 * K * 129) * sizeof(float);  // 132096
        hipFuncSetAttribute((const void*)surfm_fused,
                            hipFuncAttributeMaxDynamicSharedMemorySize, (int)shmem);
        const int blocks = N * ND + 4 * N;
        surfm_fused<<<blocks, 256, shmem, stream>>>(C12, C21, F1, F2, E1, E2, T1, T2,
                                                    ev1, ev2, desc, out, N, ND, V, CF);
        return;
    }

    char* ws = (char*)d_ws;
    unsigned short* Abf = (unsigned short*)ws;
    unsigned short* Ebf = (unsigned short*)(ws + ABF);
    float* Fbf = (float*)(ws + ABF + EBF);
    char* Cbf = ws + ABF + EBF + FBF;
    char* Mbf = ws + ABF + EBF + FBF + CBF;
    float* Mpart = (float*)(ws + base);

    surfm_conv<<<2944, 256, 0, stream>>>(T1, T2, E1, E2, F1, F2, C12, C21, desc,
                                         Abf, Ebf, Fbf, Cbf, V, CF);

    if (mode == 1)
        hipMemsetAsync(Mpart, 0, MP1, stream);

    const size_t shmem1 = 53248;    // A dbuf 32K + w 20K
    hipFuncSetAttribute((const void*)surfm_stage1,
                        hipFuncAttributeMaxDynamicSharedMemorySize, (int)shmem1);
    surfm_stage1<<<416, 512, shmem1, stream>>>((const char*)Abf, (const char*)Ebf,
                                               Fbf, Mpart, (mode == 2) ? 400 : 0);

    const size_t shmemM = (size_t)128 * 132 * 4;   // 67584
    hipFuncSetAttribute((const void*)surfm_mconv,
                        hipFuncAttributeMaxDynamicSharedMemorySize, (int)shmemM);
    surfm_mconv<<<400, 256, shmemM, stream>>>(Mpart, (mode == 2) ? 2 : 1, Mbf);

    const size_t shmem2 = 132096;
    hipFuncSetAttribute((const void*)surfm_stage2,
                        hipFuncAttributeMaxDynamicSharedMemorySize, (int)shmem2);
    surfm_stage2<<<N * ND + 4 * N, 256, shmem2, stream>>>(C12, C21, ev1, ev2,
                                                          Cbf, Mbf, out, N, ND);
}